// Round 1
// baseline (6515.288 us; speedup 1.0000x reference)
//
#include <hip/hip_runtime.h>
#include <math.h>

#define NB 4
#define CINC 128
#define NF 64
#define NPIX 16384
#define DK 256
#define DV 512
#define QKSCALE 0.4204482f

// workspace offsets (floats)
#define OFF_XUP   0L          // [4][128][128][128]  8,388,608
#define OFF_NBUF  8388608L    // [4][64][16384]      4,194,304
#define OFF_XA    12582912L   // [4][64][16384]      4,194,304
#define OFF_VC    16777216L   // [4][512][4096]      8,388,608
#define OFF_CTXP  25165824L   // [4][128][256][64]   8,388,608
#define OFF_SPART 33554432L   // [4][128][256]         131,072
#define OFF_CTX   33685504L   // [4][256][64]           65,536
#define OFF_W1N   33751040L   // [128][64][9]           73,728
#define OFF_W2N   33824768L   // [64][64][9]            36,864
#define OFF_OWT   33861632L   // [2][512][64]           65,536
#define OFF_F2WT  33927168L   // [2][128][64]           16,384
#define OFF_STYLE 33943552L   // [4][64]                   256
#define OFF_RGBS  33943808L   // [4][3][128][128]      196,608
#define OFF_RGBUP 34140416L   // [4][3][256][256]      786,432
// total 34,926,848 floats = 139.7 MB

#define CDIV(a,b) (((a)+(b)-1)/(b))

// ---------------- bilinear 2x upsample (half-pixel, edge-clamped == jax.image.resize) ----
__global__ void up2_kernel(const float* __restrict__ in, float* __restrict__ out,
                           int C, int Hin, int Win) {
  int Hout = Hin * 2, Wout = Win * 2;
  int total = NB * C * Hout * Wout;
  int idx = blockIdx.x * 256 + threadIdx.x;
  if (idx >= total) return;
  int ox = idx % Wout; int t = idx / Wout;
  int oy = t % Hout; t /= Hout;
  // t = b*C + c
  float iy = oy * 0.5f - 0.25f;
  float ix = ox * 0.5f - 0.25f;
  int y0 = (int)floorf(iy); float wy = iy - (float)y0;
  int x0 = (int)floorf(ix); float wx = ix - (float)x0;
  int ylo = y0 < 0 ? 0 : y0;           // y0 <= Hin-1 always
  int yhi = y0 + 1 > Hin - 1 ? Hin - 1 : y0 + 1;
  int xlo = x0 < 0 ? 0 : x0;
  int xhi = x0 + 1 > Win - 1 ? Win - 1 : x0 + 1;
  const float* base = in + (long)t * Hin * Win;
  float v00 = base[ylo * Win + xlo], v01 = base[ylo * Win + xhi];
  float v10 = base[yhi * Win + xlo], v11 = base[yhi * Win + xhi];
  float v = (1.f - wy) * ((1.f - wx) * v00 + wx * v01) + wy * ((1.f - wx) * v10 + wx * v11);
  out[(long)t * Hout * Wout + oy * Wout + ox] = v;
}

// ---------------- demod weight prep: wt[ci][64][9] = 2W * rsqrt(sum((2W)^2)+eps) --------
__global__ void wnorm_kernel(const float* __restrict__ W, float* __restrict__ wt, int CI) {
  int co = blockIdx.x;          // 64 blocks
  int n = CI * 9;
  __shared__ float red[256];
  float s = 0.f;
  for (int idx = threadIdx.x; idx < n; idx += 256) {
    float w2 = 2.0f * W[co * n + idx];
    s += w2 * w2;
  }
  red[threadIdx.x] = s;
  __syncthreads();
  for (int off = 128; off > 0; off >>= 1) {
    if (threadIdx.x < off) red[threadIdx.x] += red[threadIdx.x + off];
    __syncthreads();
  }
  float sc = rsqrtf(red[0] + 1e-8f);
  for (int idx = threadIdx.x; idx < n; idx += 256) {
    int ci = idx / 9, k = idx - ci * 9;
    wt[(ci * 64 + co) * 9 + k] = 2.0f * W[co * n + idx] * sc;
  }
}

// ---------------- batched transpose: src[2][R][C] -> dst[2][C][R] ------------------------
__global__ void transpose_kernel(const float* __restrict__ src, float* __restrict__ dst,
                                 int R, int Cc) {
  int tot = 2 * R * Cc;
  int idx = blockIdx.x * 256 + threadIdx.x;
  if (idx >= tot) return;
  int i = idx / (R * Cc);
  int rem = idx - i * R * Cc;
  int r = rem / Cc, c = rem - r * Cc;
  dst[i * R * Cc + c * R + r] = src[idx];
}

// ---------------- style = istyle @ style_w^T + style_b ----------------------------------
__global__ void style_kernel(const float* __restrict__ istyle, const float* __restrict__ sw,
                             const float* __restrict__ sb, float* __restrict__ styleb) {
  int b = threadIdx.x >> 6;
  int c = threadIdx.x & 63;
  float a = 0.f;
  const float* ip = istyle + b * 512;
  const float* wp = sw + c * 512;
  for (int l = 0; l < 512; ++l) a += ip[l] * wp[l];
  styleb[b * 64 + c] = a + sb[c];
}

// ---------------- V chunk GEMM: Vc[b][512][4096] = vw @ noise[:, n0:n0+4096] ------------
__global__ __launch_bounds__(256) void vgemm_kernel(const float* __restrict__ nz,
                                                    const float* __restrict__ vw,
                                                    float* __restrict__ Vc, int n0) {
  int b = blockIdx.y;
  int lane = threadIdx.x & 63;
  int rg = threadIdx.x >> 6;               // 4 groups x 128 rows
  int nl = blockIdx.x * 64 + lane;         // local 0..4095
  int n = n0 + nl;
  float xcol[64];
  const float* nzb = nz + (long)b * NF * NPIX + n;
#pragma unroll
  for (int c = 0; c < 64; ++c) xcol[c] = nzb[c * NPIX];
  float* vcb = Vc + ((long)b * DV + rg * 128) * 4096 + nl;
  const float* vwp = vw + rg * 128 * 64;
#pragma unroll 2
  for (int r = 0; r < 128; ++r) {
    float a = 0.f;
#pragma unroll
    for (int c = 0; c < 64; ++c) a += vwp[r * 64 + c] * xcol[c];
    vcb[(long)r * 4096] = a;
  }
}

// ---------------- ctx partials: thread = k-row, chunk of 128 pixels ----------------------
__global__ __launch_bounds__(256) void ctxpart_kernel(const float* __restrict__ nz,
                                                      const float* __restrict__ kw,
                                                      const float* __restrict__ Vc,
                                                      float* __restrict__ ctxp,
                                                      float* __restrict__ spart, int vc) {
  int b = blockIdx.y;
  int cc = blockIdx.x;              // 0..31 within V chunk
  int ch = vc * 32 + cc;            // global chunk 0..127
  int t = threadIdx.x;              // k-row 0..255
  int h = t >> 5;
  int n0g = ch * 128;
  int nl0 = cc * 128;
  float kwreg[64];
  const float4* kwp = (const float4*)(kw + t * 64);
#pragma unroll
  for (int c4 = 0; c4 < 16; ++c4) {
    float4 v = kwp[c4];
    kwreg[c4 * 4 + 0] = v.x; kwreg[c4 * 4 + 1] = v.y;
    kwreg[c4 * 4 + 2] = v.z; kwreg[c4 * 4 + 3] = v.w;
  }
  float acc[64];
#pragma unroll
  for (int e = 0; e < 64; ++e) acc[e] = 0.f;
  float sacc = 0.f;
  const float4* nz4 = (const float4*)(nz + (long)b * NF * NPIX + n0g);    // row stride 4096 f4
  const float4* vc4 = (const float4*)(Vc + ((long)b * DV + h * 64) * 4096 + nl0); // stride 1024 f4
  for (int n4 = 0; n4 < 32; ++n4) {
    float k0 = 0.f, k1 = 0.f, k2 = 0.f, k3 = 0.f;
#pragma unroll
    for (int c = 0; c < 64; ++c) {
      float4 z = nz4[c * 4096 + n4];
      k0 += kwreg[c] * z.x; k1 += kwreg[c] * z.y;
      k2 += kwreg[c] * z.z; k3 += kwreg[c] * z.w;
    }
    float p0 = __expf(k0 * QKSCALE), p1 = __expf(k1 * QKSCALE);
    float p2 = __expf(k2 * QKSCALE), p3 = __expf(k3 * QKSCALE);
    sacc += p0 + p1 + p2 + p3;
#pragma unroll
    for (int e = 0; e < 64; ++e) {
      float4 vv = vc4[e * 1024 + n4];
      acc[e] += p0 * vv.x + p1 * vv.y + p2 * vv.z + p3 * vv.w;
    }
  }
  float* cp = ctxp + (((long)b * 128 + ch) * 256 + t) * 64;
#pragma unroll
  for (int e = 0; e < 64; ++e) cp[e] = acc[e];
  spart[((long)b * 128 + ch) * 256 + t] = sacc;
}

// ---------------- merge ctx partials ----------------------------------------------------
__global__ void ctxmerge_kernel(const float* __restrict__ ctxp, const float* __restrict__ spart,
                                float* __restrict__ ctx) {
  int idx = blockIdx.x * 256 + threadIdx.x;     // 65536
  int e = idx & 63;
  int t = (idx >> 6) & 255;
  int b = idx >> 14;
  float cs = 0.f, ss = 0.f;
  for (int ch = 0; ch < 128; ++ch) {
    cs += ctxp[(((long)b * 128 + ch) * 256 + t) * 64 + e];
    ss += spart[((long)b * 128 + ch) * 256 + t];
  }
  ctx[((long)b * 256 + t) * 64 + e] = cs / ss;
}

// ---------------- per-pixel: q-softmax*ctx -> ow -> residual -> FF -> residual ----------
__global__ __launch_bounds__(256) void attnd_kernel(
    const float* __restrict__ nz, const float* __restrict__ qw,
    const float* __restrict__ ctx, const float* __restrict__ owT,
    const float* __restrict__ ob, const float* __restrict__ gap,
    const float* __restrict__ f1w, const float* __restrict__ f1b,
    const float* __restrict__ f2wT, const float* __restrict__ f2b,
    const float* __restrict__ gfp, float* __restrict__ nout) {
  int b = blockIdx.y;
  int n = blockIdx.x * 256 + threadIdx.x;
  float ga = gap[0], gf = gfp[0];
  float xcol[64];
  const float* nzb = nz + (long)b * NF * NPIX + n;
#pragma unroll
  for (int c = 0; c < 64; ++c) xcol[c] = nzb[c * NPIX];
  float o[64];
#pragma unroll
  for (int c = 0; c < 64; ++c) o[c] = ob[c];
  const float* ctxb = ctx + (long)b * 256 * 64;
  for (int h = 0; h < 8; ++h) {
    float qv[32];
#pragma unroll
    for (int d = 0; d < 32; ++d) {
      float a = 0.f;
      const float* qp = qw + (h * 32 + d) * 64;
#pragma unroll
      for (int c = 0; c < 64; ++c) a += qp[c] * xcol[c];
      qv[d] = a * QKSCALE;
    }
    float s = 0.f;
#pragma unroll
    for (int d = 0; d < 32; ++d) { qv[d] = __expf(qv[d]); s += qv[d]; }
    float inv = 1.0f / s;
#pragma unroll
    for (int d = 0; d < 32; ++d) qv[d] *= inv;
    for (int e = 0; e < 64; ++e) {
      float outv = 0.f;
      const float* cp = ctxb + (h * 32) * 64 + e;
#pragma unroll
      for (int d = 0; d < 32; ++d) outv += qv[d] * cp[d * 64];
      const float* op = owT + (h * 64 + e) * 64;
#pragma unroll
      for (int c = 0; c < 64; ++c) o[c] += op[c] * outv;
    }
  }
  float y[64];
#pragma unroll
  for (int c = 0; c < 64; ++c) y[c] = xcol[c] + ga * o[c];
  float ff[64];
#pragma unroll
  for (int c = 0; c < 64; ++c) ff[c] = f2b[c];
#pragma unroll 2
  for (int j = 0; j < 128; ++j) {
    float a = f1b[j];
    const float* fp = f1w + j * 64;
#pragma unroll
    for (int c = 0; c < 64; ++c) a += fp[c] * y[c];
    a = a > 0.f ? a : 0.2f * a;
    const float* gp = f2wT + j * 64;
#pragma unroll
    for (int c = 0; c < 64; ++c) ff[c] += gp[c] * a;
  }
  float* outb = nout + (long)b * NF * NPIX + n;
#pragma unroll
  for (int c = 0; c < 64; ++c) outb[c * NPIX] = y[c] + gf * ff[c];
}

// ---------------- 3x3 conv (zero pad), +add, lrelu; wt layout [ci][64co][9] -------------
__global__ __launch_bounds__(256) void conv3x3_kernel(const float* __restrict__ in, int CI,
                                                      const float* __restrict__ wt,
                                                      const float* __restrict__ addn,
                                                      float* __restrict__ out) {
  int bz = blockIdx.z; int b = bz >> 2; int cog = bz & 3;
  int x0 = blockIdx.x * 16, y0 = blockIdx.y * 16;
  int tx = threadIdx.x & 15, ty = threadIdx.x >> 4;
  __shared__ float tile[324];   // 18x18
  float acc[16];
#pragma unroll
  for (int i = 0; i < 16; ++i) acc[i] = 0.f;
  for (int ci = 0; ci < CI; ++ci) {
    for (int idx = threadIdx.x; idx < 324; idx += 256) {
      int r = idx / 18; int c2 = idx - r * 18;
      int yy = y0 - 1 + r, xx = x0 - 1 + c2;
      float v = 0.f;
      if (yy >= 0 && yy < 128 && xx >= 0 && xx < 128)
        v = in[((long)(b * CI + ci)) * NPIX + yy * 128 + xx];
      tile[idx] = v;
    }
    __syncthreads();
    float tv[9];
#pragma unroll
    for (int dy = 0; dy < 3; ++dy)
#pragma unroll
      for (int dx = 0; dx < 3; ++dx) tv[dy * 3 + dx] = tile[(ty + dy) * 18 + tx + dx];
    const float* wp = wt + (ci * 64 + cog * 16) * 9;
#pragma unroll
    for (int co = 0; co < 16; ++co)
#pragma unroll
      for (int k = 0; k < 9; ++k) acc[co] += wp[co * 9 + k] * tv[k];
    __syncthreads();
  }
  int gy = y0 + ty, gx = x0 + tx;
#pragma unroll
  for (int co = 0; co < 16; ++co) {
    int c = cog * 16 + co;
    long oidx = ((long)(b * 64 + c)) * NPIX + gy * 128 + gx;
    float a = acc[co] + addn[oidx];
    a = a > 0.f ? a : 0.2f * a;
    out[oidx] = a;
  }
}

// ---------------- modulated 1x1 rgb conv + prev_rgb -------------------------------------
__global__ void rgbsmall_kernel(const float* __restrict__ xfin, const float* __restrict__ rgbw,
                                const float* __restrict__ styleb, const float* __restrict__ prev,
                                float* __restrict__ rgbs) {
  int idx = blockIdx.x * 256 + threadIdx.x;   // 65536
  int n = idx & (NPIX - 1);
  int b = idx >> 14;
  float a0 = prev[(b * 3 + 0) * NPIX + n];
  float a1 = prev[(b * 3 + 1) * NPIX + n];
  float a2 = prev[(b * 3 + 2) * NPIX + n];
  const float* xb = xfin + (long)b * NF * NPIX + n;
  const float* sb = styleb + b * 64;
#pragma unroll
  for (int c = 0; c < 64; ++c) {
    float xv = xb[c * NPIX];
    float m = sb[c] + 1.0f;
    a0 += rgbw[c] * m * xv;
    a1 += rgbw[64 + c] * m * xv;
    a2 += rgbw[128 + c] * m * xv;
  }
  rgbs[(b * 3 + 0) * NPIX + n] = a0;
  rgbs[(b * 3 + 1) * NPIX + n] = a1;
  rgbs[(b * 3 + 2) * NPIX + n] = a2;
}

// ---------------- 3x3 [1,2,1] blur, zero pad --------------------------------------------
__global__ void blur_kernel(const float* __restrict__ in, float* __restrict__ out) {
  int idx = blockIdx.x * 256 + threadIdx.x;   // 786432
  int X = idx & 255;
  int Y = (idx >> 8) & 255;
  int bc = idx >> 16;                          // 0..11
  const float* base = in + (long)bc * 65536;
  float s = 0.f;
  const float wt3[3] = {1.f, 2.f, 1.f};
#pragma unroll
  for (int dy = -1; dy <= 1; ++dy) {
    int yy = Y + dy;
    if (yy < 0 || yy > 255) continue;
#pragma unroll
    for (int dx = -1; dx <= 1; ++dx) {
      int xx = X + dx;
      if (xx < 0 || xx > 255) continue;
      s += wt3[dy + 1] * wt3[dx + 1] * base[yy * 256 + xx];
    }
  }
  out[idx] = s * (1.0f / 16.0f);
}

extern "C" void kernel_launch(void* const* d_in, const int* in_sizes, int n_in,
                              void* d_out, int out_size, void* d_ws, size_t ws_size,
                              hipStream_t stream) {
  (void)in_sizes; (void)n_in; (void)out_size; (void)ws_size;
  const float* x        = (const float*)d_in[0];
  const float* prev_rgb = (const float*)d_in[1];
  const float* istyle   = (const float*)d_in[2];
  const float* noise1   = (const float*)d_in[3];
  const float* noise2   = (const float*)d_in[4];
  const float* conv1_w  = (const float*)d_in[5];
  const float* conv2_w  = (const float*)d_in[6];
  const float* style_w  = (const float*)d_in[7];
  const float* style_b  = (const float*)d_in[8];
  const float* rgb_w    = (const float*)d_in[9];
  const float* qw       = (const float*)d_in[10];
  const float* kw       = (const float*)d_in[11];
  const float* vw       = (const float*)d_in[12];
  const float* ow       = (const float*)d_in[13];
  const float* ob       = (const float*)d_in[14];
  const float* ga       = (const float*)d_in[15];
  const float* f1w      = (const float*)d_in[16];
  const float* f1b      = (const float*)d_in[17];
  const float* f2w      = (const float*)d_in[18];
  const float* f2b      = (const float*)d_in[19];
  const float* gf       = (const float*)d_in[20];
  float* out_x   = (float*)d_out;
  float* out_rgb = out_x + 4194304;
  float* ws = (float*)d_ws;

  float* xup   = ws + OFF_XUP;
  float* nbuf  = ws + OFF_NBUF;
  float* xa    = ws + OFF_XA;
  float* Vc    = ws + OFF_VC;
  float* ctxp  = ws + OFF_CTXP;
  float* spart = ws + OFF_SPART;
  float* ctx   = ws + OFF_CTX;
  float* w1n   = ws + OFF_W1N;
  float* w2n   = ws + OFF_W2N;
  float* owT   = ws + OFF_OWT;
  float* f2wT  = ws + OFF_F2WT;
  float* styleb= ws + OFF_STYLE;
  float* rgbs  = ws + OFF_RGBS;
  float* rgbup = ws + OFF_RGBUP;

  // prep
  wnorm_kernel<<<64, 256, 0, stream>>>(conv1_w, w1n, 128);
  wnorm_kernel<<<64, 256, 0, stream>>>(conv2_w, w2n, 64);
  transpose_kernel<<<CDIV(2 * 64 * 512, 256), 256, 0, stream>>>(ow, owT, 64, 512);
  transpose_kernel<<<CDIV(2 * 64 * 128, 256), 256, 0, stream>>>(f2w, f2wT, 64, 128);
  style_kernel<<<1, 256, 0, stream>>>(istyle, style_w, style_b, styleb);

  // upsample x
  up2_kernel<<<CDIV(NB * 128 * 128 * 128, 256), 256, 0, stream>>>(x, xup, 128, 64, 64);

  // two attention+FF blocks
  for (int i = 0; i < 2; ++i) {
    const float* nz    = (i == 0) ? noise1 : noise2;
    const float* qw_i  = qw + i * DK * NF;
    const float* kw_i  = kw + i * DK * NF;
    const float* vw_i  = vw + i * DV * NF;
    const float* owT_i = owT + i * DV * NF;
    const float* ob_i  = ob + i * NF;
    const float* f1w_i = f1w + i * 128 * 64;
    const float* f1b_i = f1b + i * 128;
    const float* f2wT_i= f2wT + i * 128 * 64;
    const float* f2b_i = f2b + i * NF;
    for (int vc = 0; vc < 4; ++vc) {
      vgemm_kernel<<<dim3(64, NB), 256, 0, stream>>>(nz, vw_i, Vc, vc * 4096);
      ctxpart_kernel<<<dim3(32, NB), 256, 0, stream>>>(nz, kw_i, Vc, ctxp, spart, vc);
    }
    ctxmerge_kernel<<<256, 256, 0, stream>>>(ctxp, spart, ctx);
    attnd_kernel<<<dim3(64, NB), 256, 0, stream>>>(nz, qw_i, ctx, owT_i, ob_i, ga + i,
                                                   f1w_i, f1b_i, f2wT_i, f2b_i, gf + i, nbuf);
    if (i == 0) {
      conv3x3_kernel<<<dim3(8, 8, NB * 4), 256, 0, stream>>>(xup, 128, w1n, nbuf, xa);
    } else {
      conv3x3_kernel<<<dim3(8, 8, NB * 4), 256, 0, stream>>>(xa, 64, w2n, nbuf, out_x);
    }
  }

  // rgb path
  rgbsmall_kernel<<<CDIV(NB * NPIX, 256), 256, 0, stream>>>(out_x, rgb_w, styleb, prev_rgb, rgbs);
  up2_kernel<<<CDIV(NB * 3 * 256 * 256, 256), 256, 0, stream>>>(rgbs, rgbup, 3, 128, 128);
  blur_kernel<<<CDIV(NB * 3 * 256 * 256, 256), 256, 0, stream>>>(rgbup, out_rgb);
}

// Round 2
// 1592.459 us; speedup vs baseline: 4.0913x; 4.0913x over previous
//
#include <hip/hip_runtime.h>
#include <math.h>

#define NB 4
#define NF 64
#define NPIX 16384
#define DK 256
#define DV 512
#define QKSCALE 0.4204482f

// workspace offsets (floats)
#define OFF_XUP   0L          // [4][128][128][128]  8,388,608
#define OFF_NBUF  8388608L    // [4][64][16384]      4,194,304
#define OFF_XA    12582912L   // [4][64][16384]      4,194,304
#define OFF_GPART 16777216L   // [4][128][256][64]   8,388,608
#define OFF_SPART 25165824L   // [4][128][256]         131,072
#define OFF_MT    25296896L   // [4][256][64]           65,536
#define OFF_W1N   25362432L   // [128][64][9]           73,728
#define OFF_W2N   25436160L   // [64][64][9]            36,864
#define OFF_F2WT  25473024L   // [2][128][64]           16,384
#define OFF_STYLE 25489408L   // [4][64]                   256
#define OFF_RGBS  25489664L   // [4][3][128][128]      196,608
#define OFF_RGBUP 25686272L   // [4][3][256][256]      786,432
// total 26,472,704 floats = 105.9 MB

#define CDIV(a,b) (((a)+(b)-1)/(b))

// ---------------- bilinear 2x upsample (half-pixel, edge-clamped == jax.image.resize) ----
__global__ void up2_kernel(const float* __restrict__ in, float* __restrict__ out,
                           int C, int Hin, int Win) {
  int Hout = Hin * 2, Wout = Win * 2;
  int total = NB * C * Hout * Wout;
  int idx = blockIdx.x * 256 + threadIdx.x;
  if (idx >= total) return;
  int ox = idx % Wout; int t = idx / Wout;
  int oy = t % Hout; t /= Hout;
  float iy = oy * 0.5f - 0.25f;
  float ix = ox * 0.5f - 0.25f;
  int y0 = (int)floorf(iy); float wy = iy - (float)y0;
  int x0 = (int)floorf(ix); float wx = ix - (float)x0;
  int ylo = y0 < 0 ? 0 : y0;
  int yhi = y0 + 1 > Hin - 1 ? Hin - 1 : y0 + 1;
  int xlo = x0 < 0 ? 0 : x0;
  int xhi = x0 + 1 > Win - 1 ? Win - 1 : x0 + 1;
  const float* base = in + (long)t * Hin * Win;
  float v00 = base[ylo * Win + xlo], v01 = base[ylo * Win + xhi];
  float v10 = base[yhi * Win + xlo], v11 = base[yhi * Win + xhi];
  float v = (1.f - wy) * ((1.f - wx) * v00 + wx * v01) + wy * ((1.f - wx) * v10 + wx * v11);
  out[(long)t * Hout * Wout + oy * Wout + ox] = v;
}

// ---------------- demod weight prep: wt[ci][64][9] = 2W * rsqrt(sum((2W)^2)+eps) --------
__global__ void wnorm_kernel(const float* __restrict__ W, float* __restrict__ wt, int CI) {
  int co = blockIdx.x;          // 64 blocks
  int n = CI * 9;
  __shared__ float red[256];
  float s = 0.f;
  for (int idx = threadIdx.x; idx < n; idx += 256) {
    float w2 = 2.0f * W[co * n + idx];
    s += w2 * w2;
  }
  red[threadIdx.x] = s;
  __syncthreads();
  for (int off = 128; off > 0; off >>= 1) {
    if (threadIdx.x < off) red[threadIdx.x] += red[threadIdx.x + off];
    __syncthreads();
  }
  float sc = rsqrtf(red[0] + 1e-8f);
  for (int idx = threadIdx.x; idx < n; idx += 256) {
    int ci = idx / 9, k = idx - ci * 9;
    wt[(ci * 64 + co) * 9 + k] = 2.0f * W[co * n + idx] * sc;
  }
}

// ---------------- batched transpose: src[2][R][C] -> dst[2][C][R] ------------------------
__global__ void transpose_kernel(const float* __restrict__ src, float* __restrict__ dst,
                                 int R, int Cc) {
  int tot = 2 * R * Cc;
  int idx = blockIdx.x * 256 + threadIdx.x;
  if (idx >= tot) return;
  int i = idx / (R * Cc);
  int rem = idx - i * R * Cc;
  int r = rem / Cc, c = rem - r * Cc;
  dst[i * R * Cc + c * R + r] = src[idx];
}

// ---------------- style = istyle @ style_w^T + style_b ----------------------------------
__global__ void style_kernel(const float* __restrict__ istyle, const float* __restrict__ sw,
                             const float* __restrict__ sb, float* __restrict__ styleb) {
  int b = threadIdx.x >> 6;
  int c = threadIdx.x & 63;
  float a = 0.f;
  const float* ip = istyle + b * 512;
  const float* wp = sw + c * 512;
  for (int l = 0; l < 512; ++l) a += ip[l] * wp[l];
  styleb[b * 64 + c] = a + sb[c];
}

// ---------------- G partials: G[d,c] = sum_n exp(scale*k[d,n]) * x[c,n] -----------------
// grid (128 chunks, NB), block 256 (thread = d-row), chunk = 128 pixels
__global__ __launch_bounds__(256, 2) void gpart_kernel(const float* __restrict__ nz,
                                                       const float* __restrict__ kw,
                                                       float* __restrict__ Gpart,
                                                       float* __restrict__ spart) {
  int b = blockIdx.y, ch = blockIdx.x;
  int t = threadIdx.x;
  __shared__ float Xl[64 * 128];            // [c][n] natural layout, 32 KB
  float4* Xl4 = (float4*)Xl;
  const float4* x4 = (const float4*)(nz + (long)b * NF * NPIX) + ch * 32;  // row stride 4096 f4
  for (int idx = t; idx < 2048; idx += 256) {
    int c = idx >> 5, n4 = idx & 31;
    Xl4[c * 32 + n4] = x4[(long)c * 4096 + n4];
  }
  __syncthreads();
  float kwreg[64];
  const float4* kwp = (const float4*)(kw + t * 64);
#pragma unroll
  for (int i = 0; i < 16; ++i) {
    float4 v = kwp[i];
    kwreg[4 * i] = v.x; kwreg[4 * i + 1] = v.y; kwreg[4 * i + 2] = v.z; kwreg[4 * i + 3] = v.w;
  }
  float acc[64];
#pragma unroll
  for (int c = 0; c < 64; ++c) acc[c] = 0.f;
  float sacc = 0.f;
  for (int sub = 0; sub < 16; ++sub) {      // 2 float4-pixels (8 px) per iteration
    float p[8];
#pragma unroll
    for (int j = 0; j < 2; ++j) {
      int n4 = sub * 2 + j;
      float k0 = 0.f, k1 = 0.f, k2 = 0.f, k3 = 0.f;
#pragma unroll
      for (int c = 0; c < 64; ++c) {
        float4 z = Xl4[c * 32 + n4];
        k0 += kwreg[c] * z.x; k1 += kwreg[c] * z.y;
        k2 += kwreg[c] * z.z; k3 += kwreg[c] * z.w;
      }
      p[4 * j]     = __expf(k0 * QKSCALE);
      p[4 * j + 1] = __expf(k1 * QKSCALE);
      p[4 * j + 2] = __expf(k2 * QKSCALE);
      p[4 * j + 3] = __expf(k3 * QKSCALE);
    }
#pragma unroll
    for (int j = 0; j < 8; ++j) sacc += p[j];
    asm volatile("" ::: "memory");          // prevent CSE keeping 512 LDS floats live
#pragma unroll
    for (int j = 0; j < 2; ++j) {
      int n4 = sub * 2 + j;
#pragma unroll
      for (int c = 0; c < 64; ++c) {
        float4 z = Xl4[c * 32 + n4];
        acc[c] += p[4 * j] * z.x + p[4 * j + 1] * z.y + p[4 * j + 2] * z.z + p[4 * j + 3] * z.w;
      }
    }
  }
  float4* gp = (float4*)(Gpart + (((long)b * 128 + ch) * 256 + t) * 64);
#pragma unroll
  for (int c4 = 0; c4 < 16; ++c4)
    gp[c4] = make_float4(acc[4 * c4], acc[4 * c4 + 1], acc[4 * c4 + 2], acc[4 * c4 + 3]);
  spart[((long)b * 128 + ch) * 256 + t] = sacc;
}

// ---------------- merge G, compute ctx, fold ow into Mt[d][c] ---------------------------
// grid (16 d-tiles, NB), block 256
__global__ void ctxM_kernel(const float* __restrict__ Gpart, const float* __restrict__ spart,
                            const float* __restrict__ vw, const float* __restrict__ ow,
                            float* __restrict__ Mt) {
  int b = blockIdx.y, dt = blockIdx.x * 16;
  int h = dt >> 5;                          // 16 d-rows never straddle a head (32-aligned)
  __shared__ float Gs[16][68];
  __shared__ float ctxs[16][68];
  __shared__ float ss[16];
  int t = threadIdx.x;
  for (int idx = t; idx < 1024; idx += 256) {
    int dl = idx >> 6, c = idx & 63;
    float s = 0.f;
    const float* gp = Gpart + ((long)b * 128 * 256 + (dt + dl)) * 64 + c;
    for (int ch = 0; ch < 128; ++ch) s += gp[(long)ch * 16384];
    Gs[dl][c] = s;
  }
  if (t < 16) {
    float s = 0.f;
    const float* sp = spart + (long)b * 128 * 256 + dt + t;
    for (int ch = 0; ch < 128; ++ch) s += sp[ch * 256];
    ss[t] = s;
  }
  __syncthreads();
  // ctx[dl][e] = (1/ss[dl]) * dot_c(Gs[dl], vw[(h*64+e)])
  for (int idx = t; idx < 1024; idx += 256) {
    int dl = idx & 15, e = idx >> 4;
    const float* vp = vw + (h * 64 + e) * 64;
    float a = 0.f;
#pragma unroll
    for (int c = 0; c < 64; ++c) a += Gs[dl][c] * vp[c];
    ctxs[dl][e] = a / ss[dl];
  }
  __syncthreads();
  // Mt[b][dt+dl][c] = sum_e ow[c][h*64+e] * ctx[dl][e]
  for (int idx = t; idx < 1024; idx += 256) {
    int dl = idx & 15, c = idx >> 4;
    const float* op = ow + c * 512 + h * 64;
    float a = 0.f;
#pragma unroll
    for (int e = 0; e < 64; ++e) a += op[e] * ctxs[dl][e];
    Mt[((long)b * 256 + dt + dl) * 64 + c] = a;
  }
}

// ---------------- per-pixel: q-softmax -> Mt -> residual -> FF -> residual --------------
// grid (256, NB), block 64 (one pixel per thread)
__global__ __launch_bounds__(64, 2) void attnd2_kernel(
    const float* __restrict__ nz, const float* __restrict__ qw,
    const float* __restrict__ Mt, const float* __restrict__ ob,
    const float* __restrict__ gap, const float* __restrict__ f1w,
    const float* __restrict__ f1b, const float* __restrict__ f2wT,
    const float* __restrict__ f2b, const float* __restrict__ gfp,
    float* __restrict__ nout) {
  int b = blockIdx.y;
  int n = blockIdx.x * 64 + threadIdx.x;
  __shared__ float qs[64 * 33];             // per-thread 32-entry strip (pad 33)
  float* myqs = qs + threadIdx.x * 33;
  float ga = gap[0], gf = gfp[0];
  float xcol[64];
  const float* nzb = nz + (long)b * NF * NPIX + n;
#pragma unroll
  for (int c = 0; c < 64; ++c) xcol[c] = nzb[c * NPIX];
  float o[64];
#pragma unroll
  for (int c = 0; c < 64; ++c) o[c] = ob[c];
  for (int h = 0; h < 8; ++h) {
    float s = 0.f;
    for (int d = 0; d < 32; ++d) {
      const float* qp = qw + (h * 32 + d) * 64;
      float a0 = 0.f, a1 = 0.f;
#pragma unroll
      for (int c = 0; c < 32; ++c) {
        a0 += qp[c] * xcol[c];
        a1 += qp[32 + c] * xcol[32 + c];
      }
      float e = __expf((a0 + a1) * QKSCALE);
      myqs[d] = e;
      s += e;
    }
    float inv = 1.0f / s;
    const float* Mtb = Mt + ((long)b * 256 + h * 32) * 64;
    for (int d = 0; d < 32; ++d) {
      float qsd = myqs[d] * inv;
      const float* mp = Mtb + d * 64;
#pragma unroll
      for (int c = 0; c < 64; ++c) o[c] += qsd * mp[c];
    }
  }
#pragma unroll
  for (int c = 0; c < 64; ++c) xcol[c] += ga * o[c];   // y, in place
#pragma unroll
  for (int c = 0; c < 64; ++c) o[c] = f2b[c];          // reuse o as ff accumulator
  for (int j = 0; j < 128; ++j) {
    const float* fp = f1w + j * 64;
    float a0 = 0.f, a1 = 0.f;
#pragma unroll
    for (int c = 0; c < 32; ++c) {
      a0 += fp[c] * xcol[c];
      a1 += fp[32 + c] * xcol[32 + c];
    }
    float a = a0 + a1 + f1b[j];
    a = a > 0.f ? a : 0.2f * a;
    const float* gp = f2wT + j * 64;
#pragma unroll
    for (int c = 0; c < 64; ++c) o[c] += gp[c] * a;
  }
  float* outb = nout + (long)b * NF * NPIX + n;
#pragma unroll
  for (int c = 0; c < 64; ++c) outb[c * NPIX] = xcol[c] + gf * o[c];
}

// ---------------- 3x3 conv (zero pad), +add, lrelu; wt layout [ci][64co][9] -------------
__global__ __launch_bounds__(256) void conv3x3_kernel(const float* __restrict__ in, int CI,
                                                      const float* __restrict__ wt,
                                                      const float* __restrict__ addn,
                                                      float* __restrict__ out) {
  int bz = blockIdx.z; int b = bz >> 2; int cog = bz & 3;
  int x0 = blockIdx.x * 16, y0 = blockIdx.y * 16;
  int tx = threadIdx.x & 15, ty = threadIdx.x >> 4;
  __shared__ float tile[4][324];            // 4 input channels staged per round
  float acc[16];
#pragma unroll
  for (int i = 0; i < 16; ++i) acc[i] = 0.f;
  for (int cb = 0; cb < CI; cb += 4) {
    for (int idx = threadIdx.x; idx < 1296; idx += 256) {
      int q = idx / 324; int pos = idx - q * 324;
      int r = pos / 18; int c2 = pos - r * 18;
      int yy = y0 - 1 + r, xx = x0 - 1 + c2;
      float v = 0.f;
      if (yy >= 0 && yy < 128 && xx >= 0 && xx < 128)
        v = in[((long)(b * CI + cb + q)) * NPIX + yy * 128 + xx];
      tile[q][pos] = v;
    }
    __syncthreads();
#pragma unroll
    for (int q = 0; q < 4; ++q) {
      float tv[9];
#pragma unroll
      for (int dy = 0; dy < 3; ++dy)
#pragma unroll
        for (int dx = 0; dx < 3; ++dx) tv[dy * 3 + dx] = tile[q][(ty + dy) * 18 + tx + dx];
      const float* wp = wt + ((cb + q) * 64 + cog * 16) * 9;
#pragma unroll
      for (int co = 0; co < 16; ++co)
#pragma unroll
        for (int k = 0; k < 9; ++k) acc[co] += wp[co * 9 + k] * tv[k];
    }
    __syncthreads();
  }
  int gy = y0 + ty, gx = x0 + tx;
#pragma unroll
  for (int co = 0; co < 16; ++co) {
    int c = cog * 16 + co;
    long oidx = ((long)(b * 64 + c)) * NPIX + gy * 128 + gx;
    float a = acc[co] + addn[oidx];
    a = a > 0.f ? a : 0.2f * a;
    out[oidx] = a;
  }
}

// ---------------- modulated 1x1 rgb conv + prev_rgb -------------------------------------
__global__ void rgbsmall_kernel(const float* __restrict__ xfin, const float* __restrict__ rgbw,
                                const float* __restrict__ styleb, const float* __restrict__ prev,
                                float* __restrict__ rgbs) {
  int idx = blockIdx.x * 256 + threadIdx.x;   // 65536
  int n = idx & (NPIX - 1);
  int b = idx >> 14;
  float a0 = prev[(b * 3 + 0) * NPIX + n];
  float a1 = prev[(b * 3 + 1) * NPIX + n];
  float a2 = prev[(b * 3 + 2) * NPIX + n];
  const float* xb = xfin + (long)b * NF * NPIX + n;
  const float* sb = styleb + b * 64;
#pragma unroll
  for (int c = 0; c < 64; ++c) {
    float xv = xb[c * NPIX];
    float m = sb[c] + 1.0f;
    a0 += rgbw[c] * m * xv;
    a1 += rgbw[64 + c] * m * xv;
    a2 += rgbw[128 + c] * m * xv;
  }
  rgbs[(b * 3 + 0) * NPIX + n] = a0;
  rgbs[(b * 3 + 1) * NPIX + n] = a1;
  rgbs[(b * 3 + 2) * NPIX + n] = a2;
}

// ---------------- 3x3 [1,2,1] blur, zero pad --------------------------------------------
__global__ void blur_kernel(const float* __restrict__ in, float* __restrict__ out) {
  int idx = blockIdx.x * 256 + threadIdx.x;   // 786432
  int X = idx & 255;
  int Y = (idx >> 8) & 255;
  int bc = idx >> 16;                          // 0..11
  const float* base = in + (long)bc * 65536;
  float s = 0.f;
  const float wt3[3] = {1.f, 2.f, 1.f};
#pragma unroll
  for (int dy = -1; dy <= 1; ++dy) {
    int yy = Y + dy;
    if (yy < 0 || yy > 255) continue;
#pragma unroll
    for (int dx = -1; dx <= 1; ++dx) {
      int xx = X + dx;
      if (xx < 0 || xx > 255) continue;
      s += wt3[dy + 1] * wt3[dx + 1] * base[yy * 256 + xx];
    }
  }
  out[idx] = s * (1.0f / 16.0f);
}

extern "C" void kernel_launch(void* const* d_in, const int* in_sizes, int n_in,
                              void* d_out, int out_size, void* d_ws, size_t ws_size,
                              hipStream_t stream) {
  (void)in_sizes; (void)n_in; (void)out_size; (void)ws_size;
  const float* x        = (const float*)d_in[0];
  const float* prev_rgb = (const float*)d_in[1];
  const float* istyle   = (const float*)d_in[2];
  const float* noise1   = (const float*)d_in[3];
  const float* noise2   = (const float*)d_in[4];
  const float* conv1_w  = (const float*)d_in[5];
  const float* conv2_w  = (const float*)d_in[6];
  const float* style_w  = (const float*)d_in[7];
  const float* style_b  = (const float*)d_in[8];
  const float* rgb_w    = (const float*)d_in[9];
  const float* qw       = (const float*)d_in[10];
  const float* kw       = (const float*)d_in[11];
  const float* vw       = (const float*)d_in[12];
  const float* ow       = (const float*)d_in[13];
  const float* ob       = (const float*)d_in[14];
  const float* ga       = (const float*)d_in[15];
  const float* f1w      = (const float*)d_in[16];
  const float* f1b      = (const float*)d_in[17];
  const float* f2w      = (const float*)d_in[18];
  const float* f2b      = (const float*)d_in[19];
  const float* gf       = (const float*)d_in[20];
  float* out_x   = (float*)d_out;
  float* out_rgb = out_x + 4194304;
  float* ws = (float*)d_ws;

  float* xup    = ws + OFF_XUP;
  float* nbuf   = ws + OFF_NBUF;
  float* xa     = ws + OFF_XA;
  float* Gpart  = ws + OFF_GPART;
  float* spart  = ws + OFF_SPART;
  float* Mt     = ws + OFF_MT;
  float* w1n    = ws + OFF_W1N;
  float* w2n    = ws + OFF_W2N;
  float* f2wT   = ws + OFF_F2WT;
  float* styleb = ws + OFF_STYLE;
  float* rgbs   = ws + OFF_RGBS;
  float* rgbup  = ws + OFF_RGBUP;

  // prep
  wnorm_kernel<<<64, 256, 0, stream>>>(conv1_w, w1n, 128);
  wnorm_kernel<<<64, 256, 0, stream>>>(conv2_w, w2n, 64);
  transpose_kernel<<<CDIV(2 * 64 * 128, 256), 256, 0, stream>>>(f2w, f2wT, 64, 128);
  style_kernel<<<1, 256, 0, stream>>>(istyle, style_w, style_b, styleb);

  // upsample x
  up2_kernel<<<CDIV(NB * 128 * 128 * 128, 256), 256, 0, stream>>>(x, xup, 128, 64, 64);

  // two attention+FF blocks
  for (int i = 0; i < 2; ++i) {
    const float* nz     = (i == 0) ? noise1 : noise2;
    const float* qw_i   = qw + i * DK * NF;
    const float* kw_i   = kw + i * DK * NF;
    const float* vw_i   = vw + i * DV * NF;
    const float* ow_i   = ow + i * NF * DV;
    const float* ob_i   = ob + i * NF;
    const float* f1w_i  = f1w + i * 128 * 64;
    const float* f1b_i  = f1b + i * 128;
    const float* f2wT_i = f2wT + i * 128 * 64;
    const float* f2b_i  = f2b + i * NF;
    gpart_kernel<<<dim3(128, NB), 256, 0, stream>>>(nz, kw_i, Gpart, spart);
    ctxM_kernel<<<dim3(16, NB), 256, 0, stream>>>(Gpart, spart, vw_i, ow_i, Mt);
    attnd2_kernel<<<dim3(256, NB), 64, 0, stream>>>(nz, qw_i, Mt, ob_i, ga + i,
                                                    f1w_i, f1b_i, f2wT_i, f2b_i, gf + i, nbuf);
    if (i == 0) {
      conv3x3_kernel<<<dim3(8, 8, NB * 4), 256, 0, stream>>>(xup, 128, w1n, nbuf, xa);
    } else {
      conv3x3_kernel<<<dim3(8, 8, NB * 4), 256, 0, stream>>>(xa, 64, w2n, nbuf, out_x);
    }
  }

  // rgb path
  rgbsmall_kernel<<<CDIV(NB * NPIX, 256), 256, 0, stream>>>(out_x, rgb_w, styleb, prev_rgb, rgbs);
  up2_kernel<<<CDIV(NB * 3 * 256 * 256, 256), 256, 0, stream>>>(rgbs, rgbup, 3, 128, 128);
  blur_kernel<<<CDIV(NB * 3 * 256 * 256, 256), 256, 0, stream>>>(rgbup, out_rgb);
}

// Round 3
// 827.734 us; speedup vs baseline: 7.8712x; 1.9239x over previous
//
#include <hip/hip_runtime.h>
#include <math.h>

#define NB 4
#define NF 64
#define NPIX 16384
#define DK 256
#define DV 512
#define QKSCALE 0.4204482f

typedef __attribute__((ext_vector_type(8))) short bf16x8;
typedef __attribute__((ext_vector_type(4))) float f32x4;
#define MFMA16(a, b, c) __builtin_amdgcn_mfma_f32_16x16x32_bf16(a, b, c, 0, 0, 0)

__device__ __forceinline__ short f2bf(float f) {
  unsigned u = __builtin_bit_cast(unsigned, f);
  unsigned r = (u + 0x7FFFu + ((u >> 16) & 1u)) >> 16;
  return (short)r;
}

// workspace offsets (float units)
#define OFF_XUP    0L          // [4][128][128][128]   8,388,608
#define OFF_NBUF   8388608L    // [4][64][16384]       4,194,304
#define OFF_XA     12582912L   // [4][64][16384]       4,194,304
#define OFF_GPART  16777216L   // [4][128][256][80]   10,485,760
#define OFF_W1N    27262976L   // [128][64][9]            73,728
#define OFF_W2N    27336704L   // [64][64][9]             36,864
#define OFF_STYLE  27373568L   // [4][64]                    256
#define OFF_RGBS   27373824L   // [4][3][128][128]       196,608
#define OFF_RGBUP  27570432L   // [4][3][256][256]       786,432
#define OFF_QWB    28356864L   // bf16 [2][256][64] -> 16384 f
#define OFF_KWB    28373248L   // bf16 [2][256][64] -> 16384 f
#define OFF_F1WB   28389632L   // bf16 [2][128][64] ->  8192 f
#define OFF_F2WB   28397824L   // bf16 [2][64][128] ->  8192 f
#define OFF_MTT    28406016L   // bf16 [4][64][256] -> 32768 f
// total 28,438,784 floats = 113.8 MB

#define CDIV(a,b) (((a)+(b)-1)/(b))

// ---------------- fp32 -> bf16 convert ---------------------------------------------------
__global__ void cvt_kernel(const float* __restrict__ s, short* __restrict__ d, int n) {
  int i = blockIdx.x * 256 + threadIdx.x;
  if (i < n) d[i] = f2bf(s[i]);
}

// ---------------- bilinear 2x upsample (half-pixel, edge-clamped) ------------------------
__global__ void up2_kernel(const float* __restrict__ in, float* __restrict__ out,
                           int C, int Hin, int Win) {
  int Hout = Hin * 2, Wout = Win * 2;
  int total = NB * C * Hout * Wout;
  int idx = blockIdx.x * 256 + threadIdx.x;
  if (idx >= total) return;
  int ox = idx % Wout; int t = idx / Wout;
  int oy = t % Hout; t /= Hout;
  float iy = oy * 0.5f - 0.25f;
  float ix = ox * 0.5f - 0.25f;
  int y0 = (int)floorf(iy); float wy = iy - (float)y0;
  int x0 = (int)floorf(ix); float wx = ix - (float)x0;
  int ylo = y0 < 0 ? 0 : y0;
  int yhi = y0 + 1 > Hin - 1 ? Hin - 1 : y0 + 1;
  int xlo = x0 < 0 ? 0 : x0;
  int xhi = x0 + 1 > Win - 1 ? Win - 1 : x0 + 1;
  const float* base = in + (long)t * Hin * Win;
  float v00 = base[ylo * Win + xlo], v01 = base[ylo * Win + xhi];
  float v10 = base[yhi * Win + xlo], v11 = base[yhi * Win + xhi];
  float v = (1.f - wy) * ((1.f - wx) * v00 + wx * v01) + wy * ((1.f - wx) * v10 + wx * v11);
  out[(long)t * Hout * Wout + oy * Wout + ox] = v;
}

// ---------------- demod weight prep ------------------------------------------------------
__global__ void wnorm_kernel(const float* __restrict__ W, float* __restrict__ wt, int CI) {
  int co = blockIdx.x;
  int n = CI * 9;
  __shared__ float red[256];
  float s = 0.f;
  for (int idx = threadIdx.x; idx < n; idx += 256) {
    float w2 = 2.0f * W[co * n + idx];
    s += w2 * w2;
  }
  red[threadIdx.x] = s;
  __syncthreads();
  for (int off = 128; off > 0; off >>= 1) {
    if (threadIdx.x < off) red[threadIdx.x] += red[threadIdx.x + off];
    __syncthreads();
  }
  float sc = rsqrtf(red[0] + 1e-8f);
  for (int idx = threadIdx.x; idx < n; idx += 256) {
    int ci = idx / 9, k = idx - ci * 9;
    wt[(ci * 64 + co) * 9 + k] = 2.0f * W[co * n + idx] * sc;
  }
}

// ---------------- style ------------------------------------------------------------------
__global__ void style_kernel(const float* __restrict__ istyle, const float* __restrict__ sw,
                             const float* __restrict__ sb, float* __restrict__ styleb) {
  int b = threadIdx.x >> 6;
  int c = threadIdx.x & 63;
  float a = 0.f;
  const float* ip = istyle + b * 512;
  const float* wp = sw + c * 512;
  for (int l = 0; l < 512; ++l) a += ip[l] * wp[l];
  styleb[b * 64 + c] = a + sb[c];
}

// ---------------- pk: Gpart[b][ch][256][80] = exp(kw@X) @ [X^T | 1 | 0...] ---------------
// grid (128, NB), block 256. LDS: Xb[80][136]bf16 @0, Xt[128][72]bf16 @21760, Ph[64][136]bf16 @40192
__global__ __launch_bounds__(256, 2) void pk_kernel(const float* __restrict__ nz,
                                                    const short* __restrict__ kwb,
                                                    float* __restrict__ Gpart) {
  __shared__ __attribute__((aligned(16))) char lds[57600];
  int b = blockIdx.y, ch = blockIdx.x;
  int tid = threadIdx.x;
  int w = tid >> 6, lane = tid & 63, quad = lane >> 4, l15 = lane & 15;
  int n0 = ch * 128;
  short* Xb = (short*)lds;             // row stride 272 B (136 bf16)
  short* Xt = (short*)(lds + 21760);   // row stride 144 B (72 bf16)
  short* Ph = (short*)(lds + 40192);   // row stride 272 B
  // stage X -> Xb[c][n], Xt[n][c]
  for (int k = 0; k < 32; ++k) {
    int idx = tid + k * 256;
    int c = idx >> 7, n = idx & 127;
    float v = nz[((long)b * 64 + c) * NPIX + n0 + n];
    short bv = f2bf(v);
    Xb[c * 136 + n] = bv;
    Xt[n * 72 + c] = bv;
  }
  // ones / zeros rows 64..79
  for (int k = 0; k < 8; ++k) {
    int idx = tid + k * 256;
    int c = 64 + (idx >> 7), n = idx & 127;
    Xb[c * 136 + n] = (c == 64) ? (short)0x3F80 : (short)0;
  }
  __syncthreads();
  for (int q = 0; q < 4; ++q) {
    // GEMM1: P[64d x 128n] = kw_q @ X  (wave w handles ntiles 2w, 2w+1)
    f32x4 acc[2][4];
#pragma unroll
    for (int j = 0; j < 2; ++j)
#pragma unroll
      for (int dt = 0; dt < 4; ++dt) acc[j][dt] = (f32x4){0.f, 0.f, 0.f, 0.f};
#pragma unroll
    for (int j = 0; j < 2; ++j) {
      int ntile = 2 * w + j;
#pragma unroll
      for (int ks = 0; ks < 2; ++ks) {
        bf16x8 bfr = *(const bf16x8*)(Xt + (ntile * 16 + l15) * 72 + ks * 32 + quad * 8);
#pragma unroll
        for (int dt = 0; dt < 4; ++dt) {
          bf16x8 afr = *(const bf16x8*)(kwb + ((q * 64 + dt * 16 + l15) * 64 + ks * 32 + quad * 8));
          acc[j][dt] = MFMA16(afr, bfr, acc[j][dt]);
        }
      }
    }
#pragma unroll
    for (int j = 0; j < 2; ++j) {
      int ntile = 2 * w + j;
#pragma unroll
      for (int dt = 0; dt < 4; ++dt)
#pragma unroll
        for (int r = 0; r < 4; ++r) {
          float p = __expf(acc[j][dt][r] * QKSCALE);
          Ph[(dt * 16 + quad * 4 + r) * 136 + ntile * 16 + l15] = f2bf(p);
        }
    }
    __syncthreads();
    // GEMM2: Gq[64d x 80c] = Ph @ Xb^T   (wave w -> dtile w, ctiles 0..4)
#pragma unroll
    for (int ct = 0; ct < 5; ++ct) {
      f32x4 g = (f32x4){0.f, 0.f, 0.f, 0.f};
#pragma unroll
      for (int ks = 0; ks < 4; ++ks) {
        bf16x8 afr = *(const bf16x8*)(Ph + (w * 16 + l15) * 136 + ks * 32 + quad * 8);
        bf16x8 bfr = *(const bf16x8*)(Xb + (ct * 16 + l15) * 136 + ks * 32 + quad * 8);
        g = MFMA16(afr, bfr, g);
      }
#pragma unroll
      for (int r = 0; r < 4; ++r) {
        int row = q * 64 + w * 16 + quad * 4 + r;
        Gpart[(((long)b * 128 + ch) * 256 + row) * 80 + ct * 16 + l15] = g[r];
      }
    }
    __syncthreads();
  }
}

// ---------------- ctxM: merge Gpart -> ctx -> MtT (bf16 [b][64c][256d]) ------------------
__global__ void ctxM_kernel(const float* __restrict__ Gpart, const float* __restrict__ vw,
                            const float* __restrict__ ow, short* __restrict__ MtTb) {
  int b = blockIdx.y, dt = blockIdx.x * 16;
  int h = dt >> 5;
  __shared__ float Gs[16][81];
  __shared__ float ctxs[16][68];
  int t = threadIdx.x;
  for (int idx = t; idx < 1280; idx += 256) {
    int dl = idx / 80, c = idx - dl * 80;
    float s = 0.f;
    const float* gp = Gpart + ((long)b * 128 * 256 + (dt + dl)) * 80 + c;
    for (int ch = 0; ch < 128; ++ch) s += gp[(long)ch * 20480];
    Gs[dl][c] = s;
  }
  __syncthreads();
  for (int idx = t; idx < 1024; idx += 256) {
    int dl = idx & 15, e = idx >> 4;
    const float* vp = vw + (h * 64 + e) * 64;
    float a = 0.f;
#pragma unroll
    for (int c = 0; c < 64; ++c) a += Gs[dl][c] * vp[c];
    ctxs[dl][e] = a / Gs[dl][64];
  }
  __syncthreads();
  for (int idx = t; idx < 1024; idx += 256) {
    int dl = idx & 15, c = idx >> 4;
    const float* op = ow + c * 512 + h * 64;
    float a = 0.f;
#pragma unroll
    for (int e = 0; e < 64; ++e) a += op[e] * ctxs[dl][e];
    MtTb[((long)b * 64 + c) * 256 + dt + dl] = f2bf(a);
  }
}

// ---------------- attnd3: fused q-softmax/out/FF, per-wave 16 px, MFMA -------------------
// grid (256, NB), block 256 (4 independent waves). Per-wave LDS 10752 B:
//   Xt[16n][72c] @ +0 ; union @ +2304: Eb[16n][264d]  -> later Yb[16n][72c] @+2304, H[16n][136j] @+4608
__global__ __launch_bounds__(256, 3) void attnd3_kernel(
    const float* __restrict__ nz, const short* __restrict__ qwb,
    const short* __restrict__ MtTb, const float* __restrict__ ob,
    const float* __restrict__ gap, const short* __restrict__ f1wb,
    const float* __restrict__ f1b, const short* __restrict__ f2wb,
    const float* __restrict__ f2b, const float* __restrict__ gfp,
    float* __restrict__ nout) {
  __shared__ __attribute__((aligned(16))) char lds[43008];
  int b = blockIdx.y;
  int tid = threadIdx.x;
  int w = tid >> 6, lane = tid & 63, quad = lane >> 4, l15 = lane & 15;
  int n0 = blockIdx.x * 64 + w * 16;
  char* base = lds + w * 10752;
  short* Xt = (short*)base;            // stride 72 bf16
  short* Eb = (short*)(base + 2304);   // stride 264 bf16
  short* Yb = (short*)(base + 2304);   // stride 72 bf16 (overlays Eb after GEMM2)
  short* Hb = (short*)(base + 4608);   // stride 136 bf16
  float ga = gap[0], gf = gfp[0];
  // stage X -> Xt[n][c] (bf16)
#pragma unroll
  for (int k = 0; k < 16; ++k) {
    int c = quad + 4 * k;
    float v = nz[((long)b * 64 + c) * NPIX + n0 + l15];
    Xt[l15 * 72 + c] = f2bf(v);
  }
  // GEMM1: Q[256d x 16n] (this wave's ntile only)
  f32x4 acc1[16];
#pragma unroll
  for (int dt = 0; dt < 16; ++dt) acc1[dt] = (f32x4){0.f, 0.f, 0.f, 0.f};
#pragma unroll
  for (int ks = 0; ks < 2; ++ks) {
    bf16x8 bfr = *(const bf16x8*)(Xt + l15 * 72 + ks * 32 + quad * 8);
#pragma unroll
    for (int dt = 0; dt < 16; ++dt) {
      bf16x8 afr = *(const bf16x8*)(qwb + ((dt * 16 + l15) * 64 + ks * 32 + quad * 8));
      acc1[dt] = MFMA16(afr, bfr, acc1[dt]);
    }
  }
  // softmax over d within each head (rows local to wave; cols need quad-reduce)
#pragma unroll
  for (int h = 0; h < 8; ++h) {
    float part = 0.f;
#pragma unroll
    for (int dd = 0; dd < 2; ++dd) {
      int dt = 2 * h + dd;
#pragma unroll
      for (int r = 0; r < 4; ++r) {
        float e = __expf(acc1[dt][r] * QKSCALE);
        acc1[dt][r] = e;
        part += e;
      }
    }
    float p2 = part + __shfl_xor(part, 16);
    float s = p2 + __shfl_xor(p2, 32);
    float inv = 1.0f / s;
#pragma unroll
    for (int dd = 0; dd < 2; ++dd) {
      int dt = 2 * h + dd;
#pragma unroll
      for (int r = 0; r < 4; ++r)
        Eb[l15 * 264 + dt * 16 + quad * 4 + r] = f2bf(acc1[dt][r] * inv);
    }
  }
  // GEMM2: o[64c x 16n] = MtT @ E'
  const short* mtb = MtTb + (long)b * 64 * 256;
  f32x4 acc2[4];
#pragma unroll
  for (int ct = 0; ct < 4; ++ct) acc2[ct] = (f32x4){0.f, 0.f, 0.f, 0.f};
#pragma unroll
  for (int ks = 0; ks < 8; ++ks) {
    bf16x8 bfr = *(const bf16x8*)(Eb + l15 * 264 + ks * 32 + quad * 8);
#pragma unroll
    for (int ct = 0; ct < 4; ++ct) {
      bf16x8 afr = *(const bf16x8*)(mtb + ((ct * 16 + l15) * 256 + ks * 32 + quad * 8));
      acc2[ct] = MFMA16(afr, bfr, acc2[ct]);
    }
  }
  // residual y = x + ga*(o + ob);  stash y (fp32 regs) and Yb (bf16 LDS)
  float yreg[4][4];
#pragma unroll
  for (int ct = 0; ct < 4; ++ct)
#pragma unroll
    for (int r = 0; r < 4; ++r) {
      int c = ct * 16 + quad * 4 + r;
      float xv = nz[((long)b * 64 + c) * NPIX + n0 + l15];
      float y = xv + ga * (acc2[ct][r] + ob[c]);
      yreg[ct][r] = y;
      Yb[l15 * 72 + c] = f2bf(y);
    }
  // GEMM3: h1[128j x 16n] = lrelu(f1w @ y + f1b)
  f32x4 acc3[8];
#pragma unroll
  for (int jt = 0; jt < 8; ++jt) acc3[jt] = (f32x4){0.f, 0.f, 0.f, 0.f};
#pragma unroll
  for (int ks = 0; ks < 2; ++ks) {
    bf16x8 bfr = *(const bf16x8*)(Yb + l15 * 72 + ks * 32 + quad * 8);
#pragma unroll
    for (int jt = 0; jt < 8; ++jt) {
      bf16x8 afr = *(const bf16x8*)(f1wb + ((jt * 16 + l15) * 64 + ks * 32 + quad * 8));
      acc3[jt] = MFMA16(afr, bfr, acc3[jt]);
    }
  }
#pragma unroll
  for (int jt = 0; jt < 8; ++jt)
#pragma unroll
    for (int r = 0; r < 4; ++r) {
      int j = jt * 16 + quad * 4 + r;
      float a = acc3[jt][r] + f1b[j];
      a = a > 0.f ? a : 0.2f * a;
      Hb[l15 * 136 + j] = f2bf(a);
    }
  // GEMM4: ff[64c x 16n] = f2w @ h1
  f32x4 acc4[4];
#pragma unroll
  for (int ct = 0; ct < 4; ++ct) acc4[ct] = (f32x4){0.f, 0.f, 0.f, 0.f};
#pragma unroll
  for (int ks = 0; ks < 4; ++ks) {
    bf16x8 bfr = *(const bf16x8*)(Hb + l15 * 136 + ks * 32 + quad * 8);
#pragma unroll
    for (int ct = 0; ct < 4; ++ct) {
      bf16x8 afr = *(const bf16x8*)(f2wb + ((ct * 16 + l15) * 128 + ks * 32 + quad * 8));
      acc4[ct] = MFMA16(afr, bfr, acc4[ct]);
    }
  }
#pragma unroll
  for (int ct = 0; ct < 4; ++ct)
#pragma unroll
    for (int r = 0; r < 4; ++r) {
      int c = ct * 16 + quad * 4 + r;
      nout[((long)b * 64 + c) * NPIX + n0 + l15] = yreg[ct][r] + gf * (acc4[ct][r] + f2b[c]);
    }
}

// ---------------- 3x3 conv (zero pad), +add, lrelu; wt layout [ci][64co][9] --------------
__global__ __launch_bounds__(256) void conv3x3_kernel(const float* __restrict__ in, int CI,
                                                      const float* __restrict__ wt,
                                                      const float* __restrict__ addn,
                                                      float* __restrict__ out) {
  int bz = blockIdx.z; int b = bz >> 2; int cog = bz & 3;
  int x0 = blockIdx.x * 16, y0 = blockIdx.y * 16;
  int tx = threadIdx.x & 15, ty = threadIdx.x >> 4;
  __shared__ float tile[4][324];
  float acc[16];
#pragma unroll
  for (int i = 0; i < 16; ++i) acc[i] = 0.f;
  for (int cb = 0; cb < CI; cb += 4) {
    for (int idx = threadIdx.x; idx < 1296; idx += 256) {
      int q = idx / 324; int pos = idx - q * 324;
      int r = pos / 18; int c2 = pos - r * 18;
      int yy = y0 - 1 + r, xx = x0 - 1 + c2;
      float v = 0.f;
      if (yy >= 0 && yy < 128 && xx >= 0 && xx < 128)
        v = in[((long)(b * CI + cb + q)) * NPIX + yy * 128 + xx];
      tile[q][pos] = v;
    }
    __syncthreads();
#pragma unroll
    for (int q = 0; q < 4; ++q) {
      float tv[9];
#pragma unroll
      for (int dy = 0; dy < 3; ++dy)
#pragma unroll
        for (int dx = 0; dx < 3; ++dx) tv[dy * 3 + dx] = tile[q][(ty + dy) * 18 + tx + dx];
      const float* wp = wt + ((cb + q) * 64 + cog * 16) * 9;
#pragma unroll
      for (int co = 0; co < 16; ++co)
#pragma unroll
        for (int k = 0; k < 9; ++k) acc[co] += wp[co * 9 + k] * tv[k];
    }
    __syncthreads();
  }
  int gy = y0 + ty, gx = x0 + tx;
#pragma unroll
  for (int co = 0; co < 16; ++co) {
    int c = cog * 16 + co;
    long oidx = ((long)(b * 64 + c)) * NPIX + gy * 128 + gx;
    float a = acc[co] + addn[oidx];
    a = a > 0.f ? a : 0.2f * a;
    out[oidx] = a;
  }
}

// ---------------- modulated 1x1 rgb conv + prev_rgb --------------------------------------
__global__ void rgbsmall_kernel(const float* __restrict__ xfin, const float* __restrict__ rgbw,
                                const float* __restrict__ styleb, const float* __restrict__ prev,
                                float* __restrict__ rgbs) {
  int idx = blockIdx.x * 256 + threadIdx.x;
  int n = idx & (NPIX - 1);
  int b = idx >> 14;
  float a0 = prev[(b * 3 + 0) * NPIX + n];
  float a1 = prev[(b * 3 + 1) * NPIX + n];
  float a2 = prev[(b * 3 + 2) * NPIX + n];
  const float* xb = xfin + (long)b * NF * NPIX + n;
  const float* sb = styleb + b * 64;
#pragma unroll
  for (int c = 0; c < 64; ++c) {
    float xv = xb[c * NPIX];
    float m = sb[c] + 1.0f;
    a0 += rgbw[c] * m * xv;
    a1 += rgbw[64 + c] * m * xv;
    a2 += rgbw[128 + c] * m * xv;
  }
  rgbs[(b * 3 + 0) * NPIX + n] = a0;
  rgbs[(b * 3 + 1) * NPIX + n] = a1;
  rgbs[(b * 3 + 2) * NPIX + n] = a2;
}

// ---------------- 3x3 [1,2,1] blur, zero pad ---------------------------------------------
__global__ void blur_kernel(const float* __restrict__ in, float* __restrict__ out) {
  int idx = blockIdx.x * 256 + threadIdx.x;
  int X = idx & 255;
  int Y = (idx >> 8) & 255;
  int bc = idx >> 16;
  const float* base = in + (long)bc * 65536;
  float s = 0.f;
  const float wt3[3] = {1.f, 2.f, 1.f};
#pragma unroll
  for (int dy = -1; dy <= 1; ++dy) {
    int yy = Y + dy;
    if (yy < 0 || yy > 255) continue;
#pragma unroll
    for (int dx = -1; dx <= 1; ++dx) {
      int xx = X + dx;
      if (xx < 0 || xx > 255) continue;
      s += wt3[dy + 1] * wt3[dx + 1] * base[yy * 256 + xx];
    }
  }
  out[idx] = s * (1.0f / 16.0f);
}

extern "C" void kernel_launch(void* const* d_in, const int* in_sizes, int n_in,
                              void* d_out, int out_size, void* d_ws, size_t ws_size,
                              hipStream_t stream) {
  (void)in_sizes; (void)n_in; (void)out_size; (void)ws_size;
  const float* x        = (const float*)d_in[0];
  const float* prev_rgb = (const float*)d_in[1];
  const float* istyle   = (const float*)d_in[2];
  const float* noise1   = (const float*)d_in[3];
  const float* noise2   = (const float*)d_in[4];
  const float* conv1_w  = (const float*)d_in[5];
  const float* conv2_w  = (const float*)d_in[6];
  const float* style_w  = (const float*)d_in[7];
  const float* style_b  = (const float*)d_in[8];
  const float* rgb_w    = (const float*)d_in[9];
  const float* qw       = (const float*)d_in[10];
  const float* kw       = (const float*)d_in[11];
  const float* vw       = (const float*)d_in[12];
  const float* ow       = (const float*)d_in[13];
  const float* ob       = (const float*)d_in[14];
  const float* ga       = (const float*)d_in[15];
  const float* f1w      = (const float*)d_in[16];
  const float* f1b      = (const float*)d_in[17];
  const float* f2w      = (const float*)d_in[18];
  const float* f2b      = (const float*)d_in[19];
  const float* gf       = (const float*)d_in[20];
  float* out_x   = (float*)d_out;
  float* out_rgb = out_x + 4194304;
  float* ws = (float*)d_ws;

  float* xup    = ws + OFF_XUP;
  float* nbuf   = ws + OFF_NBUF;
  float* xa     = ws + OFF_XA;
  float* Gpart  = ws + OFF_GPART;
  float* w1n    = ws + OFF_W1N;
  float* w2n    = ws + OFF_W2N;
  float* styleb = ws + OFF_STYLE;
  float* rgbs   = ws + OFF_RGBS;
  float* rgbup  = ws + OFF_RGBUP;
  short* qwb    = (short*)(ws + OFF_QWB);
  short* kwb    = (short*)(ws + OFF_KWB);
  short* f1wb   = (short*)(ws + OFF_F1WB);
  short* f2wb   = (short*)(ws + OFF_F2WB);
  short* MtTb   = (short*)(ws + OFF_MTT);

  // prep
  cvt_kernel<<<CDIV(2 * 256 * 64, 256), 256, 0, stream>>>(qw, qwb, 2 * 256 * 64);
  cvt_kernel<<<CDIV(2 * 256 * 64, 256), 256, 0, stream>>>(kw, kwb, 2 * 256 * 64);
  cvt_kernel<<<CDIV(2 * 128 * 64, 256), 256, 0, stream>>>(f1w, f1wb, 2 * 128 * 64);
  cvt_kernel<<<CDIV(2 * 64 * 128, 256), 256, 0, stream>>>(f2w, f2wb, 2 * 64 * 128);
  wnorm_kernel<<<64, 256, 0, stream>>>(conv1_w, w1n, 128);
  wnorm_kernel<<<64, 256, 0, stream>>>(conv2_w, w2n, 64);
  style_kernel<<<1, 256, 0, stream>>>(istyle, style_w, style_b, styleb);

  // upsample x
  up2_kernel<<<CDIV(NB * 128 * 128 * 128, 256), 256, 0, stream>>>(x, xup, 128, 64, 64);

  // two attention+FF blocks
  for (int i = 0; i < 2; ++i) {
    const float* nz    = (i == 0) ? noise1 : noise2;
    const short* qwb_i = qwb + i * DK * NF;
    const short* kwb_i = kwb + i * DK * NF;
    const float* vw_i  = vw + i * DV * NF;
    const float* ow_i  = ow + i * NF * DV;
    const float* ob_i  = ob + i * NF;
    const short* f1wb_i = f1wb + i * 128 * 64;
    const float* f1b_i  = f1b + i * 128;
    const short* f2wb_i = f2wb + i * 64 * 128;
    const float* f2b_i  = f2b + i * NF;
    pk_kernel<<<dim3(128, NB), 256, 0, stream>>>(nz, kwb_i, Gpart);
    ctxM_kernel<<<dim3(16, NB), 256, 0, stream>>>(Gpart, vw_i, ow_i, MtTb);
    attnd3_kernel<<<dim3(256, NB), 256, 0, stream>>>(nz, qwb_i, MtTb, ob_i, ga + i,
                                                     f1wb_i, f1b_i, f2wb_i, f2b_i, gf + i, nbuf);
    if (i == 0) {
      conv3x3_kernel<<<dim3(8, 8, NB * 4), 256, 0, stream>>>(xup, 128, w1n, nbuf, xa);
    } else {
      conv3x3_kernel<<<dim3(8, 8, NB * 4), 256, 0, stream>>>(xa, 64, w2n, nbuf, out_x);
    }
  }

  // rgb path
  rgbsmall_kernel<<<CDIV(NB * NPIX, 256), 256, 0, stream>>>(out_x, rgb_w, styleb, prev_rgb, rgbs);
  up2_kernel<<<CDIV(NB * 3 * 256 * 256, 256), 256, 0, stream>>>(rgbs, rgbup, 3, 128, 128);
  blur_kernel<<<CDIV(NB * 3 * 256 * 256, 256), 256, 0, stream>>>(rgbup, out_rgb);
}

// Round 4
// 495.006 us; speedup vs baseline: 13.1620x; 1.6722x over previous
//
#include <hip/hip_runtime.h>
#include <math.h>

#define NB 4
#define NF 64
#define NPIX 16384
#define DK 256
#define DV 512
#define QKSCALE 0.4204482f

typedef __attribute__((ext_vector_type(8))) short bf16x8;
typedef __attribute__((ext_vector_type(4))) float f32x4;
#define MFMA16(a, b, c) __builtin_amdgcn_mfma_f32_16x16x32_bf16(a, b, c, 0, 0, 0)

__device__ __forceinline__ short f2bf(float f) {
  unsigned u = __builtin_bit_cast(unsigned, f);
  unsigned r = (u + 0x7FFFu + ((u >> 16) & 1u)) >> 16;
  return (short)r;
}

// workspace offsets (float units)
#define OFF_XUP    0L          // [4][128][128][128] fp32   8,388,608
#define OFF_NBUF   8388608L    // [4][64][16384] fp32       4,194,304
#define OFF_XUPT   12582912L   // bf16 [4][128][128][128]   4,194,304 f-slots
#define OFF_XAT    16777216L   // bf16 [4][128][128][64]... 4,194,304 f-slots (uses half)
#define OFF_GPART  20971520L   // [4][128][256][80] fp32   10,485,760
#define OFF_WB1    31457280L   // bf16 [9][64][128]            36,864 f-slots
#define OFF_WB2    31494144L   // bf16 [9][64][64]             18,432
#define OFF_STYLE  31512576L   // [4][64]                         256
#define OFF_RGBS   31512832L   // [4][3][128][128]            196,608
#define OFF_RGBUP  31709440L   // [4][3][256][256]            786,432
#define OFF_QWB    32495872L   // bf16 [2][256][64]            16,384
#define OFF_KWB    32512256L   // bf16 [2][256][64]            16,384
#define OFF_F1WB   32528640L   // bf16 [2][128][64]             8,192
#define OFF_F2WB   32536832L   // bf16 [2][64][128]             8,192
#define OFF_MTT    32545024L   // bf16 [4][64][256]            32,768
// total 32,577,792 floats = 130.3 MB (fits: round-1 layout used 139.7 MB)

#define CDIV(a,b) (((a)+(b)-1)/(b))

// ---------------- fp32 -> bf16 convert ---------------------------------------------------
__global__ void cvt_kernel(const float* __restrict__ s, short* __restrict__ d, int n) {
  int i = blockIdx.x * 256 + threadIdx.x;
  if (i < n) d[i] = f2bf(s[i]);
}

// ---------------- bilinear 2x upsample (half-pixel, edge-clamped) ------------------------
__global__ void up2_kernel(const float* __restrict__ in, float* __restrict__ out,
                           int C, int Hin, int Win) {
  int Hout = Hin * 2, Wout = Win * 2;
  int total = NB * C * Hout * Wout;
  int idx = blockIdx.x * 256 + threadIdx.x;
  if (idx >= total) return;
  int ox = idx % Wout; int t = idx / Wout;
  int oy = t % Hout; t /= Hout;
  float iy = oy * 0.5f - 0.25f;
  float ix = ox * 0.5f - 0.25f;
  int y0 = (int)floorf(iy); float wy = iy - (float)y0;
  int x0 = (int)floorf(ix); float wx = ix - (float)x0;
  int ylo = y0 < 0 ? 0 : y0;
  int yhi = y0 + 1 > Hin - 1 ? Hin - 1 : y0 + 1;
  int xlo = x0 < 0 ? 0 : x0;
  int xhi = x0 + 1 > Win - 1 ? Win - 1 : x0 + 1;
  const float* base = in + (long)t * Hin * Win;
  float v00 = base[ylo * Win + xlo], v01 = base[ylo * Win + xhi];
  float v10 = base[yhi * Win + xlo], v11 = base[yhi * Win + xhi];
  float v = (1.f - wy) * ((1.f - wx) * v00 + wx * v01) + wy * ((1.f - wx) * v10 + wx * v11);
  out[(long)t * Hout * Wout + oy * Wout + ox] = v;
}

// ---------------- NCHW fp32 -> NHWC bf16 transpose (one (b,y) row per block) -------------
__global__ __launch_bounds__(256) void tnhwc_kernel(const float* __restrict__ in,
                                                    short* __restrict__ outT) {
  __shared__ __attribute__((aligned(16))) short tile[128 * 136];
  int b = blockIdx.y, y = blockIdx.x, tid = threadIdx.x;
  for (int it = 0; it < 64; ++it) {
    int idx = it * 256 + tid;
    int x = idx & 127, ci = idx >> 7;
    tile[x * 136 + ci] = f2bf(in[((long)(b * 128 + ci)) * 16384 + y * 128 + x]);
  }
  __syncthreads();
  long obase = ((long)(b * 128 + y)) * 128 * 128;
  int x = tid >> 1, c0 = (tid & 1) * 64;
#pragma unroll
  for (int i = 0; i < 8; ++i) {
    *(bf16x8*)(outT + obase + x * 128 + c0 + i * 8) =
        *(const bf16x8*)(tile + x * 136 + c0 + i * 8);
  }
}

// ---------------- demod weight prep -> bf16 wb[9][64][CI] --------------------------------
__global__ void wnormT_kernel(const float* __restrict__ W, short* __restrict__ wb, int CI) {
  int co = blockIdx.x;          // 64 blocks
  int n = CI * 9;
  __shared__ float red[256];
  float s = 0.f;
  for (int idx = threadIdx.x; idx < n; idx += 256) {
    float w2 = 2.0f * W[co * n + idx];
    s += w2 * w2;
  }
  red[threadIdx.x] = s;
  __syncthreads();
  for (int off = 128; off > 0; off >>= 1) {
    if (threadIdx.x < off) red[threadIdx.x] += red[threadIdx.x + off];
    __syncthreads();
  }
  float sc = rsqrtf(red[0] + 1e-8f);
  for (int idx = threadIdx.x; idx < n; idx += 256) {
    int ci = idx / 9, k = idx - ci * 9;
    wb[(k * 64 + co) * CI + ci] = f2bf(2.0f * W[co * n + idx] * sc);
  }
}

// ---------------- style ------------------------------------------------------------------
__global__ void style_kernel(const float* __restrict__ istyle, const float* __restrict__ sw,
                             const float* __restrict__ sb, float* __restrict__ styleb) {
  int b = threadIdx.x >> 6;
  int c = threadIdx.x & 63;
  float a = 0.f;
  const float* ip = istyle + b * 512;
  const float* wp = sw + c * 512;
  for (int l = 0; l < 512; ++l) a += ip[l] * wp[l];
  styleb[b * 64 + c] = a + sb[c];
}

// ---------------- MFMA 3x3 conv: NHWC bf16 in, 9 shift-GEMMs, +addn, lrelu ---------------
// grid (128 y, NB). wave w -> ntiles {2w,2w+1} x all 4 co-tiles.
__global__ __launch_bounds__(256, 4) void convmfma_kernel(
    const short* __restrict__ inT, int CI, const short* __restrict__ wb,
    const float* __restrict__ addn, float* __restrict__ out_nchw,
    short* __restrict__ out_nhwc) {
  __shared__ __attribute__((aligned(16))) short Bs[3 * 130 * 40];  // [r][xi][ci32 pad40]
  int b = blockIdx.y, y = blockIdx.x;
  int tid = threadIdx.x;
  int w = tid >> 6, lane = tid & 63, quad = lane >> 4, l15 = lane & 15;
  int KS = CI >> 5;
  f32x4 acc[2][4];
#pragma unroll
  for (int j = 0; j < 2; ++j)
#pragma unroll
    for (int ct = 0; ct < 4; ++ct) acc[j][ct] = (f32x4){0.f, 0.f, 0.f, 0.f};
  for (int ks = 0; ks < KS; ++ks) {
    if (ks) __syncthreads();
    // stage 3 halo rows (zero-padded) of current 32-ci chunk
    for (int t = tid; t < 1560; t += 256) {
      int ci8 = t & 3, xr = t >> 2;
      int xi = xr % 130, r = xr / 130;
      int gy = y + r - 1, gx = xi - 1;
      bf16x8 v = {0, 0, 0, 0, 0, 0, 0, 0};
      if (gy >= 0 && gy < 128 && gx >= 0 && gx < 128)
        v = *(const bf16x8*)(inT + (((long)(b * 128 + gy)) * 128 + gx) * CI + ks * 32 + ci8 * 8);
      *(bf16x8*)(Bs + (r * 130 + xi) * 40 + ci8 * 8) = v;
    }
    __syncthreads();
#pragma unroll
    for (int sh = 0; sh < 9; ++sh) {
      int dyv = sh / 3, dxv = sh - dyv * 3;
      const short* wrow = wb + (sh * 64 + l15) * CI + ks * 32 + quad * 8;
      bf16x8 a0 = *(const bf16x8*)(wrow);
      bf16x8 a1 = *(const bf16x8*)(wrow + 16 * CI);
      bf16x8 a2 = *(const bf16x8*)(wrow + 32 * CI);
      bf16x8 a3 = *(const bf16x8*)(wrow + 48 * CI);
#pragma unroll
      for (int j = 0; j < 2; ++j) {
        int xi = (2 * w + j) * 16 + l15 + dxv;
        bf16x8 bf = *(const bf16x8*)(Bs + (dyv * 130 + xi) * 40 + quad * 8);
        acc[j][0] = MFMA16(a0, bf, acc[j][0]);
        acc[j][1] = MFMA16(a1, bf, acc[j][1]);
        acc[j][2] = MFMA16(a2, bf, acc[j][2]);
        acc[j][3] = MFMA16(a3, bf, acc[j][3]);
      }
    }
  }
  // epilogue: + addn, lrelu, store NCHW fp32 and/or NHWC bf16
#pragma unroll
  for (int j = 0; j < 2; ++j) {
    int x = (2 * w + j) * 16 + l15;
#pragma unroll
    for (int ct = 0; ct < 4; ++ct) {
      float v[4];
#pragma unroll
      for (int r = 0; r < 4; ++r) {
        int co = ct * 16 + quad * 4 + r;
        float a = acc[j][ct][r] + addn[((long)(b * 64 + co)) * 16384 + y * 128 + x];
        v[r] = a > 0.f ? a : 0.2f * a;
      }
      if (out_nchw) {
#pragma unroll
        for (int r = 0; r < 4; ++r) {
          int co = ct * 16 + quad * 4 + r;
          out_nchw[((long)(b * 64 + co)) * 16384 + y * 128 + x] = v[r];
        }
      }
      if (out_nhwc) {
        short4 pv;
        pv.x = f2bf(v[0]); pv.y = f2bf(v[1]); pv.z = f2bf(v[2]); pv.w = f2bf(v[3]);
        *(short4*)(out_nhwc + (((long)(b * 128 + y)) * 128 + x) * 64 + ct * 16 + quad * 4) = pv;
      }
    }
  }
}

// ---------------- pk: Gpart[b][ch][256][80] = exp(kw@X) @ [X^T | 1 | 0...] ---------------
__global__ __launch_bounds__(256, 2) void pk_kernel(const float* __restrict__ nz,
                                                    const short* __restrict__ kwb,
                                                    float* __restrict__ Gpart) {
  __shared__ __attribute__((aligned(16))) char lds[57600];
  int b = blockIdx.y, ch = blockIdx.x;
  int tid = threadIdx.x;
  int w = tid >> 6, lane = tid & 63, quad = lane >> 4, l15 = lane & 15;
  int n0 = ch * 128;
  short* Xb = (short*)lds;             // row stride 136 bf16
  short* Xt = (short*)(lds + 21760);   // row stride 72 bf16
  short* Ph = (short*)(lds + 40192);   // row stride 136 bf16
  for (int k = 0; k < 32; ++k) {
    int idx = tid + k * 256;
    int c = idx >> 7, n = idx & 127;
    float v = nz[((long)b * 64 + c) * NPIX + n0 + n];
    short bv = f2bf(v);
    Xb[c * 136 + n] = bv;
    Xt[n * 72 + c] = bv;
  }
  for (int k = 0; k < 8; ++k) {
    int idx = tid + k * 256;
    int c = 64 + (idx >> 7), n = idx & 127;
    Xb[c * 136 + n] = (c == 64) ? (short)0x3F80 : (short)0;
  }
  __syncthreads();
  for (int q = 0; q < 4; ++q) {
    f32x4 acc[2][4];
#pragma unroll
    for (int j = 0; j < 2; ++j)
#pragma unroll
      for (int dt = 0; dt < 4; ++dt) acc[j][dt] = (f32x4){0.f, 0.f, 0.f, 0.f};
#pragma unroll
    for (int j = 0; j < 2; ++j) {
      int ntile = 2 * w + j;
#pragma unroll
      for (int ks = 0; ks < 2; ++ks) {
        bf16x8 bfr = *(const bf16x8*)(Xt + (ntile * 16 + l15) * 72 + ks * 32 + quad * 8);
#pragma unroll
        for (int dt = 0; dt < 4; ++dt) {
          bf16x8 afr = *(const bf16x8*)(kwb + ((q * 64 + dt * 16 + l15) * 64 + ks * 32 + quad * 8));
          acc[j][dt] = MFMA16(afr, bfr, acc[j][dt]);
        }
      }
    }
#pragma unroll
    for (int j = 0; j < 2; ++j) {
      int ntile = 2 * w + j;
#pragma unroll
      for (int dt = 0; dt < 4; ++dt)
#pragma unroll
        for (int r = 0; r < 4; ++r) {
          float p = __expf(acc[j][dt][r] * QKSCALE);
          Ph[(dt * 16 + quad * 4 + r) * 136 + ntile * 16 + l15] = f2bf(p);
        }
    }
    __syncthreads();
#pragma unroll
    for (int ct = 0; ct < 5; ++ct) {
      f32x4 g = (f32x4){0.f, 0.f, 0.f, 0.f};
#pragma unroll
      for (int ks = 0; ks < 4; ++ks) {
        bf16x8 afr = *(const bf16x8*)(Ph + (w * 16 + l15) * 136 + ks * 32 + quad * 8);
        bf16x8 bfr = *(const bf16x8*)(Xb + (ct * 16 + l15) * 136 + ks * 32 + quad * 8);
        g = MFMA16(afr, bfr, g);
      }
#pragma unroll
      for (int r = 0; r < 4; ++r) {
        int row = q * 64 + w * 16 + quad * 4 + r;
        Gpart[(((long)b * 128 + ch) * 256 + row) * 80 + ct * 16 + l15] = g[r];
      }
    }
    __syncthreads();
  }
}

// ---------------- ctxM: merge Gpart -> ctx -> MtT (bf16 [b][64c][256d]) ------------------
__global__ void ctxM_kernel(const float* __restrict__ Gpart, const float* __restrict__ vw,
                            const float* __restrict__ ow, short* __restrict__ MtTb) {
  int b = blockIdx.y, dt = blockIdx.x * 16;
  int h = dt >> 5;
  __shared__ float Gs[16][81];
  __shared__ float ctxs[16][68];
  int t = threadIdx.x;
  for (int idx = t; idx < 1280; idx += 256) {
    int dl = idx / 80, c = idx - dl * 80;
    float s = 0.f;
    const float* gp = Gpart + ((long)b * 128 * 256 + (dt + dl)) * 80 + c;
    for (int ch = 0; ch < 128; ++ch) s += gp[(long)ch * 20480];
    Gs[dl][c] = s;
  }
  __syncthreads();
  for (int idx = t; idx < 1024; idx += 256) {
    int dl = idx & 15, e = idx >> 4;
    const float* vp = vw + (h * 64 + e) * 64;
    float a = 0.f;
#pragma unroll
    for (int c = 0; c < 64; ++c) a += Gs[dl][c] * vp[c];
    ctxs[dl][e] = a / Gs[dl][64];
  }
  __syncthreads();
  for (int idx = t; idx < 1024; idx += 256) {
    int dl = idx & 15, c = idx >> 4;
    const float* op = ow + c * 512 + h * 64;
    float a = 0.f;
#pragma unroll
    for (int e = 0; e < 64; ++e) a += op[e] * ctxs[dl][e];
    MtTb[((long)b * 64 + c) * 256 + dt + dl] = f2bf(a);
  }
}

// ---------------- attnd3: fused q-softmax/out/FF, per-wave 16 px, MFMA -------------------
__global__ __launch_bounds__(256, 3) void attnd3_kernel(
    const float* __restrict__ nz, const short* __restrict__ qwb,
    const short* __restrict__ MtTb, const float* __restrict__ ob,
    const float* __restrict__ gap, const short* __restrict__ f1wb,
    const float* __restrict__ f1b, const short* __restrict__ f2wb,
    const float* __restrict__ f2b, const float* __restrict__ gfp,
    float* __restrict__ nout) {
  __shared__ __attribute__((aligned(16))) char lds[43008];
  int b = blockIdx.y;
  int tid = threadIdx.x;
  int w = tid >> 6, lane = tid & 63, quad = lane >> 4, l15 = lane & 15;
  int n0 = blockIdx.x * 64 + w * 16;
  char* base = lds + w * 10752;
  short* Xt = (short*)base;
  short* Eb = (short*)(base + 2304);
  short* Yb = (short*)(base + 2304);
  short* Hb = (short*)(base + 4608);
  float ga = gap[0], gf = gfp[0];
#pragma unroll
  for (int k = 0; k < 16; ++k) {
    int c = quad + 4 * k;
    float v = nz[((long)b * 64 + c) * NPIX + n0 + l15];
    Xt[l15 * 72 + c] = f2bf(v);
  }
  f32x4 acc1[16];
#pragma unroll
  for (int dt = 0; dt < 16; ++dt) acc1[dt] = (f32x4){0.f, 0.f, 0.f, 0.f};
#pragma unroll
  for (int ks = 0; ks < 2; ++ks) {
    bf16x8 bfr = *(const bf16x8*)(Xt + l15 * 72 + ks * 32 + quad * 8);
#pragma unroll
    for (int dt = 0; dt < 16; ++dt) {
      bf16x8 afr = *(const bf16x8*)(qwb + ((dt * 16 + l15) * 64 + ks * 32 + quad * 8));
      acc1[dt] = MFMA16(afr, bfr, acc1[dt]);
    }
  }
#pragma unroll
  for (int h = 0; h < 8; ++h) {
    float part = 0.f;
#pragma unroll
    for (int dd = 0; dd < 2; ++dd) {
      int dt = 2 * h + dd;
#pragma unroll
      for (int r = 0; r < 4; ++r) {
        float e = __expf(acc1[dt][r] * QKSCALE);
        acc1[dt][r] = e;
        part += e;
      }
    }
    float p2 = part + __shfl_xor(part, 16);
    float s = p2 + __shfl_xor(p2, 32);
    float inv = 1.0f / s;
#pragma unroll
    for (int dd = 0; dd < 2; ++dd) {
      int dt = 2 * h + dd;
#pragma unroll
      for (int r = 0; r < 4; ++r)
        Eb[l15 * 264 + dt * 16 + quad * 4 + r] = f2bf(acc1[dt][r] * inv);
    }
  }
  const short* mtb = MtTb + (long)b * 64 * 256;
  f32x4 acc2[4];
#pragma unroll
  for (int ct = 0; ct < 4; ++ct) acc2[ct] = (f32x4){0.f, 0.f, 0.f, 0.f};
#pragma unroll
  for (int ks = 0; ks < 8; ++ks) {
    bf16x8 bfr = *(const bf16x8*)(Eb + l15 * 264 + ks * 32 + quad * 8);
#pragma unroll
    for (int ct = 0; ct < 4; ++ct) {
      bf16x8 afr = *(const bf16x8*)(mtb + ((ct * 16 + l15) * 256 + ks * 32 + quad * 8));
      acc2[ct] = MFMA16(afr, bfr, acc2[ct]);
    }
  }
  float yreg[4][4];
#pragma unroll
  for (int ct = 0; ct < 4; ++ct)
#pragma unroll
    for (int r = 0; r < 4; ++r) {
      int c = ct * 16 + quad * 4 + r;
      float xv = nz[((long)b * 64 + c) * NPIX + n0 + l15];
      float y = xv + ga * (acc2[ct][r] + ob[c]);
      yreg[ct][r] = y;
      Yb[l15 * 72 + c] = f2bf(y);
    }
  f32x4 acc3[8];
#pragma unroll
  for (int jt = 0; jt < 8; ++jt) acc3[jt] = (f32x4){0.f, 0.f, 0.f, 0.f};
#pragma unroll
  for (int ks = 0; ks < 2; ++ks) {
    bf16x8 bfr = *(const bf16x8*)(Yb + l15 * 72 + ks * 32 + quad * 8);
#pragma unroll
    for (int jt = 0; jt < 8; ++jt) {
      bf16x8 afr = *(const bf16x8*)(f1wb + ((jt * 16 + l15) * 64 + ks * 32 + quad * 8));
      acc3[jt] = MFMA16(afr, bfr, acc3[jt]);
    }
  }
#pragma unroll
  for (int jt = 0; jt < 8; ++jt)
#pragma unroll
    for (int r = 0; r < 4; ++r) {
      int j = jt * 16 + quad * 4 + r;
      float a = acc3[jt][r] + f1b[j];
      a = a > 0.f ? a : 0.2f * a;
      Hb[l15 * 136 + j] = f2bf(a);
    }
  f32x4 acc4[4];
#pragma unroll
  for (int ct = 0; ct < 4; ++ct) acc4[ct] = (f32x4){0.f, 0.f, 0.f, 0.f};
#pragma unroll
  for (int ks = 0; ks < 4; ++ks) {
    bf16x8 bfr = *(const bf16x8*)(Hb + l15 * 136 + ks * 32 + quad * 8);
#pragma unroll
    for (int ct = 0; ct < 4; ++ct) {
      bf16x8 afr = *(const bf16x8*)(f2wb + ((ct * 16 + l15) * 128 + ks * 32 + quad * 8));
      acc4[ct] = MFMA16(afr, bfr, acc4[ct]);
    }
  }
#pragma unroll
  for (int ct = 0; ct < 4; ++ct)
#pragma unroll
    for (int r = 0; r < 4; ++r) {
      int c = ct * 16 + quad * 4 + r;
      nout[((long)b * 64 + c) * NPIX + n0 + l15] = yreg[ct][r] + gf * (acc4[ct][r] + f2b[c]);
    }
}

// ---------------- modulated 1x1 rgb conv + prev_rgb --------------------------------------
__global__ void rgbsmall_kernel(const float* __restrict__ xfin, const float* __restrict__ rgbw,
                                const float* __restrict__ styleb, const float* __restrict__ prev,
                                float* __restrict__ rgbs) {
  int idx = blockIdx.x * 256 + threadIdx.x;
  int n = idx & (NPIX - 1);
  int b = idx >> 14;
  float a0 = prev[(b * 3 + 0) * NPIX + n];
  float a1 = prev[(b * 3 + 1) * NPIX + n];
  float a2 = prev[(b * 3 + 2) * NPIX + n];
  const float* xb = xfin + (long)b * NF * NPIX + n;
  const float* sb = styleb + b * 64;
#pragma unroll
  for (int c = 0; c < 64; ++c) {
    float xv = xb[c * NPIX];
    float m = sb[c] + 1.0f;
    a0 += rgbw[c] * m * xv;
    a1 += rgbw[64 + c] * m * xv;
    a2 += rgbw[128 + c] * m * xv;
  }
  rgbs[(b * 3 + 0) * NPIX + n] = a0;
  rgbs[(b * 3 + 1) * NPIX + n] = a1;
  rgbs[(b * 3 + 2) * NPIX + n] = a2;
}

// ---------------- 3x3 [1,2,1] blur, zero pad ---------------------------------------------
__global__ void blur_kernel(const float* __restrict__ in, float* __restrict__ out) {
  int idx = blockIdx.x * 256 + threadIdx.x;
  int X = idx & 255;
  int Y = (idx >> 8) & 255;
  int bc = idx >> 16;
  const float* base = in + (long)bc * 65536;
  float s = 0.f;
  const float wt3[3] = {1.f, 2.f, 1.f};
#pragma unroll
  for (int dy = -1; dy <= 1; ++dy) {
    int yy = Y + dy;
    if (yy < 0 || yy > 255) continue;
#pragma unroll
    for (int dx = -1; dx <= 1; ++dx) {
      int xx = X + dx;
      if (xx < 0 || xx > 255) continue;
      s += wt3[dy + 1] * wt3[dx + 1] * base[yy * 256 + xx];
    }
  }
  out[idx] = s * (1.0f / 16.0f);
}

extern "C" void kernel_launch(void* const* d_in, const int* in_sizes, int n_in,
                              void* d_out, int out_size, void* d_ws, size_t ws_size,
                              hipStream_t stream) {
  (void)in_sizes; (void)n_in; (void)out_size; (void)ws_size;
  const float* x        = (const float*)d_in[0];
  const float* prev_rgb = (const float*)d_in[1];
  const float* istyle   = (const float*)d_in[2];
  const float* noise1   = (const float*)d_in[3];
  const float* noise2   = (const float*)d_in[4];
  const float* conv1_w  = (const float*)d_in[5];
  const float* conv2_w  = (const float*)d_in[6];
  const float* style_w  = (const float*)d_in[7];
  const float* style_b  = (const float*)d_in[8];
  const float* rgb_w    = (const float*)d_in[9];
  const float* qw       = (const float*)d_in[10];
  const float* kw       = (const float*)d_in[11];
  const float* vw       = (const float*)d_in[12];
  const float* ow       = (const float*)d_in[13];
  const float* ob       = (const float*)d_in[14];
  const float* ga       = (const float*)d_in[15];
  const float* f1w      = (const float*)d_in[16];
  const float* f1b      = (const float*)d_in[17];
  const float* f2w      = (const float*)d_in[18];
  const float* f2b      = (const float*)d_in[19];
  const float* gf       = (const float*)d_in[20];
  float* out_x   = (float*)d_out;
  float* out_rgb = out_x + 4194304;
  float* ws = (float*)d_ws;

  float* xup    = ws + OFF_XUP;
  float* nbuf   = ws + OFF_NBUF;
  short* xupT   = (short*)(ws + OFF_XUPT);
  short* xaT    = (short*)(ws + OFF_XAT);
  float* Gpart  = ws + OFF_GPART;
  short* wb1    = (short*)(ws + OFF_WB1);
  short* wb2    = (short*)(ws + OFF_WB2);
  float* styleb = ws + OFF_STYLE;
  float* rgbs   = ws + OFF_RGBS;
  float* rgbup  = ws + OFF_RGBUP;
  short* qwb    = (short*)(ws + OFF_QWB);
  short* kwb    = (short*)(ws + OFF_KWB);
  short* f1wb   = (short*)(ws + OFF_F1WB);
  short* f2wb   = (short*)(ws + OFF_F2WB);
  short* MtTb   = (short*)(ws + OFF_MTT);

  // prep
  cvt_kernel<<<CDIV(2 * 256 * 64, 256), 256, 0, stream>>>(qw, qwb, 2 * 256 * 64);
  cvt_kernel<<<CDIV(2 * 256 * 64, 256), 256, 0, stream>>>(kw, kwb, 2 * 256 * 64);
  cvt_kernel<<<CDIV(2 * 128 * 64, 256), 256, 0, stream>>>(f1w, f1wb, 2 * 128 * 64);
  cvt_kernel<<<CDIV(2 * 64 * 128, 256), 256, 0, stream>>>(f2w, f2wb, 2 * 64 * 128);
  wnormT_kernel<<<64, 256, 0, stream>>>(conv1_w, wb1, 128);
  wnormT_kernel<<<64, 256, 0, stream>>>(conv2_w, wb2, 64);
  style_kernel<<<1, 256, 0, stream>>>(istyle, style_w, style_b, styleb);

  // upsample x + NHWC bf16 transpose
  up2_kernel<<<CDIV(NB * 128 * 128 * 128, 256), 256, 0, stream>>>(x, xup, 128, 64, 64);
  tnhwc_kernel<<<dim3(128, NB), 256, 0, stream>>>(xup, xupT);

  // two attention+FF blocks, each followed by MFMA conv
  for (int i = 0; i < 2; ++i) {
    const float* nz    = (i == 0) ? noise1 : noise2;
    const short* qwb_i = qwb + i * DK * NF;
    const short* kwb_i = kwb + i * DK * NF;
    const float* vw_i  = vw + i * DV * NF;
    const float* ow_i  = ow + i * NF * DV;
    const float* ob_i  = ob + i * NF;
    const short* f1wb_i = f1wb + i * 128 * 64;
    const float* f1b_i  = f1b + i * 128;
    const short* f2wb_i = f2wb + i * 64 * 128;
    const float* f2b_i  = f2b + i * NF;
    pk_kernel<<<dim3(128, NB), 256, 0, stream>>>(nz, kwb_i, Gpart);
    ctxM_kernel<<<dim3(16, NB), 256, 0, stream>>>(Gpart, vw_i, ow_i, MtTb);
    attnd3_kernel<<<dim3(256, NB), 256, 0, stream>>>(nz, qwb_i, MtTb, ob_i, ga + i,
                                                     f1wb_i, f1b_i, f2wb_i, f2b_i, gf + i, nbuf);
    if (i == 0) {
      convmfma_kernel<<<dim3(128, NB), 256, 0, stream>>>(xupT, 128, wb1, nbuf, nullptr, xaT);
    } else {
      convmfma_kernel<<<dim3(128, NB), 256, 0, stream>>>(xaT, 64, wb2, nbuf, out_x, nullptr);
    }
  }

  // rgb path
  rgbsmall_kernel<<<CDIV(NB * NPIX, 256), 256, 0, stream>>>(out_x, rgb_w, styleb, prev_rgb, rgbs);
  up2_kernel<<<CDIV(NB * 3 * 256 * 256, 256), 256, 0, stream>>>(rgbs, rgbup, 3, 128, 128);
  blur_kernel<<<CDIV(NB * 3 * 256 * 256, 256), 256, 0, stream>>>(rgbup, out_rgb);
}